// Round 1
// baseline (1732.626 us; speedup 1.0000x reference)
//
#include <hip/hip_runtime.h>
#include <cstdint>
#include <cstddef>

// ---------------------------------------------------------------------------
// LateJoinSAGE: 3-layer GraphSAGE + post-MLP, f32 baseline.
// Pipeline per launch:
//   x0 = concat(node_feat, op_emb[opcode])              (N,148)
//   CSR build: deg -> scan -> fill (bidirectional edges)
//   per layer l: agg = mean_nbr(x); h = norm(agg@wl + bl + x@wr);
//                x = lrelu([h,x]@lin_w + lin_b)
//   g = segment_sum(x, batch); z = lrelu([g_rep, cfg]@pw1+pb1); out = z@pw2+pb2
// ---------------------------------------------------------------------------

#define LRELU(v) ((v) > 0.f ? (v) : 0.01f * (v))

constexpr int SCAN_BS = 512;

// ---------------- x0 concat ----------------
__global__ void k_concat(const float* __restrict__ nf, const int* __restrict__ opc,
                         const float* __restrict__ emb, float* __restrict__ x0, int n) {
    int idx = blockIdx.x * 256 + threadIdx.x;
    if (idx >= n * 148) return;
    int node = idx / 148;
    int f = idx - node * 148;
    float v;
    if (f < 140) v = nf[(size_t)node * 140 + f];
    else         v = emb[opc[node] * 8 + (f - 140)];
    x0[idx] = v;
}

// ---------------- CSR build ----------------
__global__ void k_deg(const int* __restrict__ ei, int* __restrict__ deg, int E) {
    int e = blockIdx.x * 256 + threadIdx.x;
    if (e >= E) return;
    int a = ei[2 * e], b = ei[2 * e + 1];
    atomicAdd(&deg[b], 1);
    atomicAdd(&deg[a], 1);
}

__global__ void k_scan1(const int* __restrict__ deg, int* __restrict__ excl,
                        int* __restrict__ partials, int n) {
    __shared__ int sm[SCAN_BS];
    int t = threadIdx.x;
    int i = blockIdx.x * SCAN_BS + t;
    int v = (i < n) ? deg[i] : 0;
    sm[t] = v;
    __syncthreads();
    for (int off = 1; off < SCAN_BS; off <<= 1) {
        int tmp = 0;
        if (t >= off) tmp = sm[t - off];
        __syncthreads();
        sm[t] += tmp;
        __syncthreads();
    }
    if (i < n) excl[i] = sm[t] - v;                  // exclusive
    if (t == SCAN_BS - 1) partials[blockIdx.x] = sm[t];
}

__global__ void k_scan2(int* __restrict__ p, int n) {  // single block
    __shared__ int sm[SCAN_BS];
    int t = threadIdx.x;
    int v = (t < n) ? p[t] : 0;
    sm[t] = v;
    __syncthreads();
    for (int off = 1; off < SCAN_BS; off <<= 1) {
        int tmp = 0;
        if (t >= off) tmp = sm[t - off];
        __syncthreads();
        sm[t] += tmp;
        __syncthreads();
    }
    if (t < n) p[t] = sm[t] - v;                     // exclusive
}

__global__ void k_scan3(int* __restrict__ rp, const int* __restrict__ partials,
                        const int* __restrict__ deg, float* __restrict__ invd,
                        int n, int total) {
    int i = blockIdx.x * SCAN_BS + threadIdx.x;
    if (i == 0) rp[n] = total;
    if (i >= n) return;
    rp[i] += partials[blockIdx.x];
    invd[i] = 1.0f / fmaxf((float)deg[i], 1.0f);
}

__global__ void k_fill(const int* __restrict__ ei, const int* __restrict__ rp,
                       int* __restrict__ fill, int* __restrict__ csr, int E) {
    int e = blockIdx.x * 256 + threadIdx.x;
    if (e >= E) return;
    int a = ei[2 * e], b = ei[2 * e + 1];
    int p1 = rp[b] + atomicAdd(&fill[b], 1);
    csr[p1] = a;
    int p2 = rp[a] + atomicAdd(&fill[a], 1);
    csr[p2] = b;
}

// ---------------- neighbor mean aggregation (wave per node) ----------------
template <int DIN>
__global__ void k_agg(const float* __restrict__ x, const int* __restrict__ rp,
                      const int* __restrict__ csr, const float* __restrict__ invd,
                      float* __restrict__ agg, int n) {
    constexpr int NR = (DIN + 63) / 64;
    int wave = threadIdx.x >> 6;
    int lane = threadIdx.x & 63;
    int node = blockIdx.x * 4 + wave;
    if (node >= n) return;
    float acc[NR];
#pragma unroll
    for (int r = 0; r < NR; r++) acc[r] = 0.f;
    int s = rp[node], e2 = rp[node + 1];
    int j = s;
    for (; j + 3 < e2; j += 4) {
        int u0 = csr[j], u1 = csr[j + 1], u2 = csr[j + 2], u3 = csr[j + 3];
#pragma unroll
        for (int r = 0; r < NR; r++) {
            int f = lane + 64 * r;
            if (f < DIN) {
                float v0 = x[(size_t)u0 * DIN + f];
                float v1 = x[(size_t)u1 * DIN + f];
                float v2 = x[(size_t)u2 * DIN + f];
                float v3 = x[(size_t)u3 * DIN + f];
                acc[r] += (v0 + v1) + (v2 + v3);
            }
        }
    }
    for (; j < e2; j++) {
        int u = csr[j];
#pragma unroll
        for (int r = 0; r < NR; r++) {
            int f = lane + 64 * r;
            if (f < DIN) acc[r] += x[(size_t)u * DIN + f];
        }
    }
    float iv = invd[node];
#pragma unroll
    for (int r = 0; r < NR; r++) {
        int f = lane + 64 * r;
        if (f < DIN) agg[(size_t)node * DIN + f] = acc[r] * iv;
    }
}

// ---------------- dense: out = act(A@W1 + B@W2 + bias) ----------------
// W row-major (K x COLS). NT rows per block. Threads: c = t%CPG, sub = t/CPG.
template <int K, int COLS, int CPG, int NSUB, int NT, int ACT>
__global__ __launch_bounds__(CPG * NSUB) void k_dense2(
    const float* __restrict__ A, const float* __restrict__ W1,
    const float* __restrict__ B, const float* __restrict__ W2,
    const float* __restrict__ bias, float* __restrict__ out, int n) {
    constexpr int TPB = CPG * NSUB;
    constexpr int K4 = K / 4;
    constexpr int NPT = NT / NSUB;
    __shared__ float4 sA[NT][K4];
    __shared__ float4 sB[NT][K4];
    int t = threadIdx.x;
    int rb = blockIdx.x * NT;
    // stage A/B tiles
    for (int i = t; i < NT * K4; i += TPB) {
        int nd = i / K4, kk = i - nd * K4;
        int row = rb + nd;
        if (row < n) {
            sA[nd][kk] = reinterpret_cast<const float4*>(A)[(size_t)row * K4 + kk];
            sB[nd][kk] = reinterpret_cast<const float4*>(B)[(size_t)row * K4 + kk];
        } else {
            sA[nd][kk] = make_float4(0.f, 0.f, 0.f, 0.f);
            sB[nd][kk] = make_float4(0.f, 0.f, 0.f, 0.f);
        }
    }
    __syncthreads();

    int c = t % CPG;
    int sub = t / CPG;
    float acc[NPT];
#pragma unroll
    for (int i = 0; i < NPT; i++) acc[i] = 0.f;

    if (c < COLS) {
        for (int k4 = 0; k4 < K4; k4++) {
            int k = k4 * 4;
            float w10 = W1[(size_t)(k + 0) * COLS + c];
            float w11 = W1[(size_t)(k + 1) * COLS + c];
            float w12 = W1[(size_t)(k + 2) * COLS + c];
            float w13 = W1[(size_t)(k + 3) * COLS + c];
            float w20 = W2[(size_t)(k + 0) * COLS + c];
            float w21 = W2[(size_t)(k + 1) * COLS + c];
            float w22 = W2[(size_t)(k + 2) * COLS + c];
            float w23 = W2[(size_t)(k + 3) * COLS + c];
#pragma unroll
            for (int i = 0; i < NPT; i++) {
                int nd = sub + i * NSUB;
                float4 a = sA[nd][k4];
                float4 b = sB[nd][k4];
                acc[i] += a.x * w10 + a.y * w11 + a.z * w12 + a.w * w13;
                acc[i] += b.x * w20 + b.y * w21 + b.z * w22 + b.w * w23;
            }
        }
        float bv = bias[c];
#pragma unroll
        for (int i = 0; i < NPT; i++) {
            int row = rb + sub + i * NSUB;
            if (row < n) {
                float v = acc[i] + bv;
                if (ACT) v = LRELU(v);
                out[(size_t)row * COLS + c] = v;
            }
        }
    }
}

// ---------------- L2 row-normalize (wave per node, in place) ----------------
template <int DIN>
__global__ void k_norm(float* __restrict__ h, int n) {
    constexpr int NR = (DIN + 63) / 64;
    int wave = threadIdx.x >> 6;
    int lane = threadIdx.x & 63;
    int node = blockIdx.x * 4 + wave;
    if (node >= n) return;
    float v[NR];
    float ss = 0.f;
#pragma unroll
    for (int r = 0; r < NR; r++) {
        int f = lane + 64 * r;
        v[r] = (f < DIN) ? h[(size_t)node * DIN + f] : 0.f;
        ss += v[r] * v[r];
    }
#pragma unroll
    for (int off = 32; off > 0; off >>= 1) ss += __shfl_xor(ss, off, 64);
    float scale = 1.0f / fmaxf(sqrtf(ss), 1e-12f);
#pragma unroll
    for (int r = 0; r < NR; r++) {
        int f = lane + 64 * r;
        if (f < DIN) h[(size_t)node * DIN + f] = v[r] * scale;
    }
}

// ---------------- global add-pool ----------------
__global__ void k_pool(const float* __restrict__ x, const int* __restrict__ batch,
                       float* __restrict__ g, int n) {
    constexpr int CHUNK = 512;
    int c = threadIdx.x & 63;
    int sub = threadIdx.x >> 6;
    int n0 = (blockIdx.x * 4 + sub) * CHUNK;
    float acc = 0.f;
    int cur = -1;
    for (int i = 0; i < CHUNK; i++) {
        int node = n0 + i;
        if (node >= n) break;
        int bg = batch[node];
        if (bg != cur) {
            if (cur >= 0) atomicAdd(&g[cur * 64 + c], acc);
            cur = bg;
            acc = 0.f;
        }
        acc += x[(size_t)node * 64 + c];
    }
    if (cur >= 0) atomicAdd(&g[cur * 64 + c], acc);
}

// ---------------- post MLP ----------------
__global__ void k_post1(const float* __restrict__ g, const float* __restrict__ cf,
                        const int* __restrict__ ncfg, const float* __restrict__ w1,
                        const float* __restrict__ b1, float* __restrict__ z,
                        int BC, int B) {
    int idx = blockIdx.x * 256 + threadIdx.x;
    if (idx >= BC * 64) return;
    int row = idx >> 6, c = idx & 63;
    int gsum = 0, gid = B - 1;
    for (int b2 = 0; b2 < B; b2++) {
        int ns = ncfg[b2];
        if (row < gsum + ns) { gid = b2; break; }
        gsum += ns;
    }
    float acc = b1[c];
#pragma unroll 4
    for (int k = 0; k < 64; k++) acc += g[gid * 64 + k] * w1[k * 64 + c];
#pragma unroll 4
    for (int k = 0; k < 24; k++) acc += cf[(size_t)row * 24 + k] * w1[(64 + k) * 64 + c];
    z[idx] = LRELU(acc);
}

__global__ void k_post2(const float* __restrict__ z, const float* __restrict__ w2,
                        const float* __restrict__ b2, float* __restrict__ out, int BC) {
    int row = blockIdx.x * 4 + (threadIdx.x >> 6);
    if (row >= BC) return;
    int c = threadIdx.x & 63;
    float v = z[(size_t)row * 64 + c] * w2[c];
#pragma unroll
    for (int off = 32; off > 0; off >>= 1) v += __shfl_xor(v, off, 64);
    if (c == 0) out[row] = v + b2[0];
}

// ---------------------------------------------------------------------------
extern "C" void kernel_launch(void* const* d_in, const int* in_sizes, int n_in,
                              void* d_out, int out_size, void* d_ws, size_t ws_size,
                              hipStream_t stream) {
    const float* node_feat = (const float*)d_in[0];
    const int*   opcode    = (const int*)d_in[1];
    const int*   ei        = (const int*)d_in[2];
    const float* cf        = (const float*)d_in[3];
    const int*   ncfg      = (const int*)d_in[4];
    const int*   batch     = (const int*)d_in[5];
    const float* emb       = (const float*)d_in[6];
    const float* wl0 = (const float*)d_in[7];
    const float* bl0 = (const float*)d_in[8];
    const float* wr0 = (const float*)d_in[9];
    const float* lw0 = (const float*)d_in[10];
    const float* lb0 = (const float*)d_in[11];
    const float* wl1 = (const float*)d_in[12];
    const float* bl1 = (const float*)d_in[13];
    const float* wr1 = (const float*)d_in[14];
    const float* lw1 = (const float*)d_in[15];
    const float* lb1 = (const float*)d_in[16];
    const float* wl2 = (const float*)d_in[17];
    const float* bl2 = (const float*)d_in[18];
    const float* wr2 = (const float*)d_in[19];
    const float* lw2 = (const float*)d_in[20];
    const float* lb2 = (const float*)d_in[21];
    const float* pw1 = (const float*)d_in[22];
    const float* pb1 = (const float*)d_in[23];
    const float* pw2 = (const float*)d_in[24];
    const float* pb2 = (const float*)d_in[25];

    const int N  = in_sizes[0] / 140;
    const int E  = in_sizes[2] / 2;
    const int B  = in_sizes[4];
    const int BC = in_sizes[3] / 24;

    char* w = (char*)d_ws;
    auto alloc = [&](size_t bytes) {
        void* p = (void*)w;
        w += (bytes + 255) & ~(size_t)255;
        return p;
    };
    int*   deg      = (int*)alloc((size_t)N * 4);
    int*   rp       = (int*)alloc((size_t)(N + 1) * 4);
    int*   fill     = (int*)alloc((size_t)N * 4);
    int*   partials = (int*)alloc(1024 * 4);
    float* invd     = (float*)alloc((size_t)N * 4);
    int*   csr      = (int*)alloc((size_t)2 * E * 4);
    float* bufA     = (float*)alloc((size_t)N * 148 * 4);
    float* bufB     = (float*)alloc((size_t)N * 148 * 4);
    float* bufC     = (float*)alloc((size_t)N * 148 * 4);
    float* gbuf     = (float*)alloc((size_t)B * 64 * 4);
    float* zp       = (float*)alloc((size_t)BC * 64 * 4);
    (void)ws_size; (void)n_in; (void)out_size;

    hipMemsetAsync(deg, 0, (size_t)N * 4, stream);
    hipMemsetAsync(fill, 0, (size_t)N * 4, stream);
    hipMemsetAsync(gbuf, 0, (size_t)B * 64 * 4, stream);

    const int NB1 = (N + SCAN_BS - 1) / SCAN_BS;

    // x0
    k_concat<<<(N * 148 + 255) / 256, 256, 0, stream>>>(node_feat, opcode, emb, bufA, N);
    // CSR
    k_deg<<<(E + 255) / 256, 256, 0, stream>>>(ei, deg, E);
    k_scan1<<<NB1, SCAN_BS, 0, stream>>>(deg, rp, partials, N);
    k_scan2<<<1, SCAN_BS, 0, stream>>>(partials, NB1);
    k_scan3<<<NB1, SCAN_BS, 0, stream>>>(rp, partials, deg, invd, N, 2 * E);
    k_fill<<<(E + 255) / 256, 256, 0, stream>>>(ei, rp, fill, csr, E);

    const int AGG_GRID   = (N + 3) / 4;
    const int DENSE_GRID = (N + 15) / 16;

    // layer 0: x = bufA (148)
    k_agg<148><<<AGG_GRID, 256, 0, stream>>>(bufA, rp, csr, invd, bufB, N);
    k_dense2<148, 148, 192, 1, 16, 0><<<DENSE_GRID, 192, 0, stream>>>(
        bufB, wl0, bufA, wr0, bl0, bufC, N);
    k_norm<148><<<AGG_GRID, 256, 0, stream>>>(bufC, N);
    k_dense2<148, 64, 64, 4, 16, 1><<<DENSE_GRID, 256, 0, stream>>>(
        bufC, lw0, bufA, lw0 + 148 * 64, lb0, bufB, N);

    // layer 1: x = bufB (64)
    k_agg<64><<<AGG_GRID, 256, 0, stream>>>(bufB, rp, csr, invd, bufC, N);
    k_dense2<64, 64, 64, 4, 16, 0><<<DENSE_GRID, 256, 0, stream>>>(
        bufC, wl1, bufB, wr1, bl1, bufA, N);
    k_norm<64><<<AGG_GRID, 256, 0, stream>>>(bufA, N);
    k_dense2<64, 64, 64, 4, 16, 1><<<DENSE_GRID, 256, 0, stream>>>(
        bufA, lw1, bufB, lw1 + 64 * 64, lb1, bufC, N);

    // layer 2: x = bufC (64)
    k_agg<64><<<AGG_GRID, 256, 0, stream>>>(bufC, rp, csr, invd, bufB, N);
    k_dense2<64, 64, 64, 4, 16, 0><<<DENSE_GRID, 256, 0, stream>>>(
        bufB, wl2, bufC, wr2, bl2, bufA, N);
    k_norm<64><<<AGG_GRID, 256, 0, stream>>>(bufA, N);
    k_dense2<64, 64, 64, 4, 16, 1><<<DENSE_GRID, 256, 0, stream>>>(
        bufA, lw2, bufC, lw2 + 64 * 64, lb2, bufB, N);

    // pool from bufB
    k_pool<<<(N + 2047) / 2048, 256, 0, stream>>>(bufB, batch, gbuf, N);
    // post MLP
    k_post1<<<(BC * 64 + 255) / 256, 256, 0, stream>>>(gbuf, cf, ncfg, pw1, pb1, zp, BC, B);
    k_post2<<<(BC + 3) / 4, 256, 0, stream>>>(zp, pw2, pb2, (float*)d_out, BC);
}

// Round 2
// 1706.721 us; speedup vs baseline: 1.0152x; 1.0152x over previous
//
#include <hip/hip_runtime.h>
#include <cstdint>
#include <cstddef>

// ---------------------------------------------------------------------------
// LateJoinSAGE round 2: bf16 node-feature storage (halves gather bytes),
// fused L2-normalize into dense kernels, NT=32 dense tiling.
// Layer-0 features padded 148 -> 160 bf16 (320B = 5 cache lines/row).
// ---------------------------------------------------------------------------

#define LRELU(v) ((v) > 0.f ? (v) : 0.01f * (v))

constexpr int SCAN_BS = 512;

__device__ inline unsigned bf16_rn(float x) {
    unsigned u = __float_as_uint(x);
    return (u + 0x7fffu + ((u >> 16) & 1u)) >> 16;
}
__device__ inline unsigned pack2(float lo, float hi) {
    return bf16_rn(lo) | (bf16_rn(hi) << 16);
}
__device__ inline float2 up2(unsigned v) {
    return make_float2(__uint_as_float(v << 16), __uint_as_float(v & 0xffff0000u));
}

// ---------------- x0 concat -> bf16 padded stride 160 (80 uints) -----------
__global__ void k_concat(const float* __restrict__ nf, const int* __restrict__ opc,
                         const float* __restrict__ emb, unsigned* __restrict__ x0,
                         int n) {
    int idx = blockIdx.x * 256 + threadIdx.x;
    if (idx >= n * 80) return;
    int node = idx / 80;
    int u = idx - node * 80;
    int f0 = 2 * u, f1 = 2 * u + 1;
    float v0 = 0.f, v1 = 0.f;
    if (f0 < 140) v0 = nf[(size_t)node * 140 + f0];
    else if (f0 < 148) v0 = emb[opc[node] * 8 + (f0 - 140)];
    if (f1 < 140) v1 = nf[(size_t)node * 140 + f1];
    else if (f1 < 148) v1 = emb[opc[node] * 8 + (f1 - 140)];
    x0[idx] = pack2(v0, v1);
}

// ---------------- CSR build ----------------
__global__ void k_deg(const int* __restrict__ ei, int* __restrict__ deg, int E) {
    int e = blockIdx.x * 256 + threadIdx.x;
    if (e >= E) return;
    int a = ei[2 * e], b = ei[2 * e + 1];
    atomicAdd(&deg[b], 1);
    atomicAdd(&deg[a], 1);
}

__global__ void k_scan1(const int* __restrict__ deg, int* __restrict__ excl,
                        int* __restrict__ partials, int n) {
    __shared__ int sm[SCAN_BS];
    int t = threadIdx.x;
    int i = blockIdx.x * SCAN_BS + t;
    int v = (i < n) ? deg[i] : 0;
    sm[t] = v;
    __syncthreads();
    for (int off = 1; off < SCAN_BS; off <<= 1) {
        int tmp = 0;
        if (t >= off) tmp = sm[t - off];
        __syncthreads();
        sm[t] += tmp;
        __syncthreads();
    }
    if (i < n) excl[i] = sm[t] - v;
    if (t == SCAN_BS - 1) partials[blockIdx.x] = sm[t];
}

__global__ void k_scan2(int* __restrict__ p, int n) {
    __shared__ int sm[SCAN_BS];
    int t = threadIdx.x;
    int v = (t < n) ? p[t] : 0;
    sm[t] = v;
    __syncthreads();
    for (int off = 1; off < SCAN_BS; off <<= 1) {
        int tmp = 0;
        if (t >= off) tmp = sm[t - off];
        __syncthreads();
        sm[t] += tmp;
        __syncthreads();
    }
    if (t < n) p[t] = sm[t] - v;
}

__global__ void k_scan3(int* __restrict__ rp, const int* __restrict__ partials,
                        const int* __restrict__ deg, float* __restrict__ invd,
                        int n, int total) {
    int i = blockIdx.x * SCAN_BS + threadIdx.x;
    if (i == 0) rp[n] = total;
    if (i >= n) return;
    rp[i] += partials[blockIdx.x];
    invd[i] = 1.0f / fmaxf((float)deg[i], 1.0f);
}

__global__ void k_fill(const int* __restrict__ ei, const int* __restrict__ rp,
                       int* __restrict__ fill, int* __restrict__ csr, int E) {
    int e = blockIdx.x * 256 + threadIdx.x;
    if (e >= E) return;
    int a = ei[2 * e], b = ei[2 * e + 1];
    int p1 = rp[b] + atomicAdd(&fill[b], 1);
    csr[p1] = a;
    int p2 = rp[a] + atomicAdd(&fill[a], 1);
    csr[p2] = b;
}

// ---------------- layer-0 aggregation: 160 bf16 / row (80 uints) -----------
// Per 4 neighbors: 4 full-wave loads (uints 0..63) + 1 full-wave ext load
// covering uints 64..79 of all 4 neighbors (lane>>4 selects neighbor).
__global__ __launch_bounds__(256) void k_agg160(
    const unsigned* __restrict__ x, const int* __restrict__ rp,
    const int* __restrict__ csr, const float* __restrict__ invd,
    unsigned* __restrict__ agg, int n) {
    int wave = threadIdx.x >> 6;
    int lane = threadIdx.x & 63;
    int node = blockIdx.x * 4 + wave;
    if (node >= n) return;
    float a0 = 0.f, a1 = 0.f, e0 = 0.f, e1 = 0.f;
    int s = rp[node], e2 = rp[node + 1];
    int q = lane >> 4;
    int pe = lane & 15;
    int j = s;
    for (; j + 4 <= e2; j += 4) {
        int u0 = csr[j], u1 = csr[j + 1], u2 = csr[j + 2], u3 = csr[j + 3];
        float2 v0 = up2(x[(size_t)u0 * 80 + lane]);
        float2 v1 = up2(x[(size_t)u1 * 80 + lane]);
        float2 v2 = up2(x[(size_t)u2 * 80 + lane]);
        float2 v3 = up2(x[(size_t)u3 * 80 + lane]);
        a0 += (v0.x + v1.x) + (v2.x + v3.x);
        a1 += (v0.y + v1.y) + (v2.y + v3.y);
        int ue = (q == 0) ? u0 : (q == 1) ? u1 : (q == 2) ? u2 : u3;
        float2 ve = up2(x[(size_t)ue * 80 + 64 + pe]);
        e0 += ve.x;
        e1 += ve.y;
    }
    for (; j < e2; j++) {
        int u = csr[j];
        float2 v = up2(x[(size_t)u * 80 + lane]);
        a0 += v.x;
        a1 += v.y;
        if (lane < 16) {
            float2 ve = up2(x[(size_t)u * 80 + 64 + lane]);
            e0 += ve.x;
            e1 += ve.y;
        }
    }
    // fold ext partials (groups of 16 lanes) down
    e0 += __shfl_xor(e0, 16, 64);
    e1 += __shfl_xor(e1, 16, 64);
    e0 += __shfl_xor(e0, 32, 64);
    e1 += __shfl_xor(e1, 32, 64);
    float iv = invd[node];
    agg[(size_t)node * 80 + lane] = pack2(a0 * iv, a1 * iv);
    if (lane < 16) agg[(size_t)node * 80 + 64 + lane] = pack2(e0 * iv, e1 * iv);
}

// ---------------- 64-dim aggregation: 2 neighbors per wave pass ------------
__global__ __launch_bounds__(256) void k_agg64(
    const unsigned* __restrict__ x, const int* __restrict__ rp,
    const int* __restrict__ csr, const float* __restrict__ invd,
    unsigned* __restrict__ agg, int n) {
    int wave = threadIdx.x >> 6;
    int lane = threadIdx.x & 63;
    int node = blockIdx.x * 4 + wave;
    if (node >= n) return;
    int p = lane & 31;
    int h = lane >> 5;
    float a0 = 0.f, a1 = 0.f;
    int s = rp[node], e2 = rp[node + 1];
    int j = s;
    for (; j + 8 <= e2; j += 8) {
        int u0 = csr[j + 0 + h];
        int u1 = csr[j + 2 + h];
        int u2 = csr[j + 4 + h];
        int u3 = csr[j + 6 + h];
        float2 v0 = up2(x[(size_t)u0 * 32 + p]);
        float2 v1 = up2(x[(size_t)u1 * 32 + p]);
        float2 v2 = up2(x[(size_t)u2 * 32 + p]);
        float2 v3 = up2(x[(size_t)u3 * 32 + p]);
        a0 += (v0.x + v1.x) + (v2.x + v3.x);
        a1 += (v0.y + v1.y) + (v2.y + v3.y);
    }
    for (; j < e2; j += 2) {
        int idx = j + h;
        if (idx < e2) {
            int u = csr[idx];
            float2 v = up2(x[(size_t)u * 32 + p]);
            a0 += v.x;
            a1 += v.y;
        }
    }
    a0 += __shfl_xor(a0, 32, 64);
    a1 += __shfl_xor(a1, 32, 64);
    if (lane < 32) {
        float iv = invd[node];
        agg[(size_t)node * 32 + p] = pack2(a0 * iv, a1 * iv);
    }
}

// ---------------- dense: out = post(A@W1 + B@W2 + bias) --------------------
// A,B bf16 (uint pairs, strides SAU/SBU uints). W row-major f32 (K x COLS).
// NORM: 0 none, 1 per-wave (CPG==64), 2 block (CPG==192, 3 waves).
// OUTF: 0 bf16 (zero-pads cols [COLS,OST)), 1 f32.
template <int K, int SAU, int SBU, int COLS, int OST, int CPG, int NSUB, int NT,
          int ACT, int NORM, int OUTF>
__global__ __launch_bounds__(CPG* NSUB) void k_dense(
    const unsigned* __restrict__ A, const float* __restrict__ W1,
    const unsigned* __restrict__ B, const float* __restrict__ W2,
    const float* __restrict__ bias, void* __restrict__ outv, int n) {
    constexpr int TPB = CPG * NSUB;
    constexpr int KU = K / 2;
    constexpr int NPT = NT / NSUB;
    __shared__ float2 sA[NT][KU];
    __shared__ float2 sB[NT][KU];
    int t = threadIdx.x;
    int rb = blockIdx.x * NT;
    for (int i = t; i < NT * KU; i += TPB) {
        int nd = i / KU, kk = i - nd * KU;
        int row = rb + nd;
        unsigned va = 0, vb = 0;
        if (row < n) {
            va = A[(size_t)row * SAU + kk];
            vb = B[(size_t)row * SBU + kk];
        }
        sA[nd][kk] = up2(va);
        sB[nd][kk] = up2(vb);
    }
    __syncthreads();

    int c = t % CPG;
    int sub = t / CPG;
    bool active = (c < COLS);
    float acc[NPT];
#pragma unroll
    for (int i = 0; i < NPT; i++) acc[i] = 0.f;

    if (active) {
        for (int k2 = 0; k2 < KU; k2++) {
            int k = 2 * k2;
            float w10 = W1[(size_t)k * COLS + c];
            float w11 = W1[(size_t)(k + 1) * COLS + c];
            float w20 = W2[(size_t)k * COLS + c];
            float w21 = W2[(size_t)(k + 1) * COLS + c];
#pragma unroll
            for (int i = 0; i < NPT; i++) {
                int nd = sub + i * NSUB;
                float2 a = sA[nd][k2];
                float2 b = sB[nd][k2];
                acc[i] += a.x * w10 + a.y * w11 + b.x * w20 + b.y * w21;
            }
        }
        float bv = bias[c];
#pragma unroll
        for (int i = 0; i < NPT; i++) acc[i] += bv;
    }

    if (NORM == 1) {
#pragma unroll
        for (int i = 0; i < NPT; i++) {
            float ss = acc[i] * acc[i];
#pragma unroll
            for (int off = 32; off > 0; off >>= 1) ss += __shfl_xor(ss, off, 64);
            acc[i] *= 1.0f / fmaxf(sqrtf(ss), 1e-12f);
        }
    } else if (NORM == 2) {
        __shared__ float red[CPG / 64][NT];
        float ss[NPT];
#pragma unroll
        for (int i = 0; i < NPT; i++) {
            ss[i] = acc[i] * acc[i];
#pragma unroll
            for (int off = 32; off > 0; off >>= 1) ss[i] += __shfl_xor(ss[i], off, 64);
        }
        if ((t & 63) == 0) {
#pragma unroll
            for (int i = 0; i < NPT; i++) red[t >> 6][i] = ss[i];
        }
        __syncthreads();
#pragma unroll
        for (int i = 0; i < NPT; i++) {
            float tot = 0.f;
#pragma unroll
            for (int w2i = 0; w2i < CPG / 64; w2i++) tot += red[w2i][i];
            acc[i] *= 1.0f / fmaxf(sqrtf(tot), 1e-12f);
        }
    }

#pragma unroll
    for (int i = 0; i < NPT; i++) {
        int row = rb + sub + i * NSUB;
        if (row >= n) continue;
        float v = acc[i];
        if (ACT) v = LRELU(v);
        if (OUTF) {
            if (active) ((float*)outv)[(size_t)row * OST + c] = v;
        } else {
            unsigned short* o = (unsigned short*)outv;
            if (active) o[(size_t)row * OST + c] = (unsigned short)bf16_rn(v);
            else if (c < OST) o[(size_t)row * OST + c] = 0;
        }
    }
}

// ---------------- global add-pool (f32 input) ----------------
__global__ void k_pool(const float* __restrict__ x, const int* __restrict__ batch,
                       float* __restrict__ g, int n) {
    constexpr int CHUNK = 512;
    int c = threadIdx.x & 63;
    int sub = threadIdx.x >> 6;
    int n0 = (blockIdx.x * 4 + sub) * CHUNK;
    float acc = 0.f;
    int cur = -1;
    for (int i = 0; i < CHUNK; i++) {
        int node = n0 + i;
        if (node >= n) break;
        int bg = batch[node];
        if (bg != cur) {
            if (cur >= 0) atomicAdd(&g[cur * 64 + c], acc);
            cur = bg;
            acc = 0.f;
        }
        acc += x[(size_t)node * 64 + c];
    }
    if (cur >= 0) atomicAdd(&g[cur * 64 + c], acc);
}

// ---------------- post MLP ----------------
__global__ void k_post1(const float* __restrict__ g, const float* __restrict__ cf,
                        const int* __restrict__ ncfg, const float* __restrict__ w1,
                        const float* __restrict__ b1, float* __restrict__ z,
                        int BC, int B) {
    int idx = blockIdx.x * 256 + threadIdx.x;
    if (idx >= BC * 64) return;
    int row = idx >> 6, c = idx & 63;
    int gsum = 0, gid = B - 1;
    for (int b2 = 0; b2 < B; b2++) {
        int ns = ncfg[b2];
        if (row < gsum + ns) { gid = b2; break; }
        gsum += ns;
    }
    float acc = b1[c];
#pragma unroll 4
    for (int k = 0; k < 64; k++) acc += g[gid * 64 + k] * w1[k * 64 + c];
#pragma unroll 4
    for (int k = 0; k < 24; k++) acc += cf[(size_t)row * 24 + k] * w1[(64 + k) * 64 + c];
    z[idx] = LRELU(acc);
}

__global__ void k_post2(const float* __restrict__ z, const float* __restrict__ w2,
                        const float* __restrict__ b2, float* __restrict__ out, int BC) {
    int row = blockIdx.x * 4 + (threadIdx.x >> 6);
    if (row >= BC) return;
    int c = threadIdx.x & 63;
    float v = z[(size_t)row * 64 + c] * w2[c];
#pragma unroll
    for (int off = 32; off > 0; off >>= 1) v += __shfl_xor(v, off, 64);
    if (c == 0) out[row] = v + b2[0];
}

// ---------------------------------------------------------------------------
extern "C" void kernel_launch(void* const* d_in, const int* in_sizes, int n_in,
                              void* d_out, int out_size, void* d_ws, size_t ws_size,
                              hipStream_t stream) {
    const float* node_feat = (const float*)d_in[0];
    const int*   opcode    = (const int*)d_in[1];
    const int*   ei        = (const int*)d_in[2];
    const float* cf        = (const float*)d_in[3];
    const int*   ncfg      = (const int*)d_in[4];
    const int*   batch     = (const int*)d_in[5];
    const float* emb       = (const float*)d_in[6];
    const float* wl0 = (const float*)d_in[7];
    const float* bl0 = (const float*)d_in[8];
    const float* wr0 = (const float*)d_in[9];
    const float* lw0 = (const float*)d_in[10];
    const float* lb0 = (const float*)d_in[11];
    const float* wl1 = (const float*)d_in[12];
    const float* bl1 = (const float*)d_in[13];
    const float* wr1 = (const float*)d_in[14];
    const float* lw1 = (const float*)d_in[15];
    const float* lb1 = (const float*)d_in[16];
    const float* wl2 = (const float*)d_in[17];
    const float* bl2 = (const float*)d_in[18];
    const float* wr2 = (const float*)d_in[19];
    const float* lw2 = (const float*)d_in[20];
    const float* lb2 = (const float*)d_in[21];
    const float* pw1 = (const float*)d_in[22];
    const float* pb1 = (const float*)d_in[23];
    const float* pw2 = (const float*)d_in[24];
    const float* pb2 = (const float*)d_in[25];

    const int N  = in_sizes[0] / 140;
    const int E  = in_sizes[2] / 2;
    const int B  = in_sizes[4];
    const int BC = in_sizes[3] / 24;

    char* w = (char*)d_ws;
    auto alloc = [&](size_t bytes) {
        void* p = (void*)w;
        w += (bytes + 255) & ~(size_t)255;
        return p;
    };
    int*      deg      = (int*)alloc((size_t)N * 4);
    int*      rp       = (int*)alloc((size_t)(N + 1) * 4);
    int*      fill     = (int*)alloc((size_t)N * 4);
    int*      partials = (int*)alloc(1024 * 4);
    float*    invd     = (float*)alloc((size_t)N * 4);
    int*      csr      = (int*)alloc((size_t)2 * E * 4);
    unsigned* X0       = (unsigned*)alloc((size_t)N * 80 * 4);   // bf16 x0, stride 160
    unsigned* AG0      = (unsigned*)alloc((size_t)N * 80 * 4);
    unsigned* H0       = (unsigned*)alloc((size_t)N * 80 * 4);
    unsigned* T0       = (unsigned*)alloc((size_t)N * 32 * 4);   // bf16 64-dim
    unsigned* T1       = (unsigned*)alloc((size_t)N * 32 * 4);
    unsigned* T2       = (unsigned*)alloc((size_t)N * 32 * 4);
    float*    X3F      = (float*)alloc((size_t)N * 64 * 4);      // final x, f32
    float*    gbuf     = (float*)alloc((size_t)B * 64 * 4);
    float*    zp       = (float*)alloc((size_t)BC * 64 * 4);
    (void)ws_size; (void)n_in; (void)out_size;

    hipMemsetAsync(deg, 0, (size_t)N * 4, stream);
    hipMemsetAsync(fill, 0, (size_t)N * 4, stream);
    hipMemsetAsync(gbuf, 0, (size_t)B * 64 * 4, stream);

    const int NB1 = (N + SCAN_BS - 1) / SCAN_BS;

    k_concat<<<(N * 80 + 255) / 256, 256, 0, stream>>>(node_feat, opcode, emb, X0, N);
    k_deg<<<(E + 255) / 256, 256, 0, stream>>>(ei, deg, E);
    k_scan1<<<NB1, SCAN_BS, 0, stream>>>(deg, rp, partials, N);
    k_scan2<<<1, SCAN_BS, 0, stream>>>(partials, NB1);
    k_scan3<<<NB1, SCAN_BS, 0, stream>>>(rp, partials, deg, invd, N, 2 * E);
    k_fill<<<(E + 255) / 256, 256, 0, stream>>>(ei, rp, fill, csr, E);

    const int AGG_GRID   = (N + 3) / 4;
    const int DENSE_GRID = (N + 31) / 32;

    // ---- layer 0 (148-dim, padded 160) ----
    k_agg160<<<AGG_GRID, 256, 0, stream>>>(X0, rp, csr, invd, AG0, N);
    // h = norm(agg@wl0 + bl0 + x0@wr0), 148 cols, block-norm, bf16 out str160
    k_dense<148, 80, 80, 148, 160, 192, 1, 32, 0, 2, 0><<<DENSE_GRID, 192, 0, stream>>>(
        AG0, wl0, X0, wr0, bl0, H0, N);
    // x1 = lrelu([h,x0]@lw0 + lb0), 64 cols, bf16 out str64
    k_dense<148, 80, 80, 64, 64, 64, 4, 32, 1, 0, 0><<<DENSE_GRID, 256, 0, stream>>>(
        H0, lw0, X0, lw0 + 148 * 64, lb0, T0, N);

    // ---- layer 1 ----
    k_agg64<<<AGG_GRID, 256, 0, stream>>>(T0, rp, csr, invd, T1, N);
    k_dense<64, 32, 32, 64, 64, 64, 4, 32, 0, 1, 0><<<DENSE_GRID, 256, 0, stream>>>(
        T1, wl1, T0, wr1, bl1, T2, N);
    k_dense<64, 32, 32, 64, 64, 64, 4, 32, 1, 0, 0><<<DENSE_GRID, 256, 0, stream>>>(
        T2, lw1, T0, lw1 + 64 * 64, lb1, T1, N);

    // ---- layer 2 ----
    k_agg64<<<AGG_GRID, 256, 0, stream>>>(T1, rp, csr, invd, T0, N);
    k_dense<64, 32, 32, 64, 64, 64, 4, 32, 0, 1, 0><<<DENSE_GRID, 256, 0, stream>>>(
        T0, wl2, T1, wr2, bl2, T2, N);
    // final x3 in f32 (protects the 12500-node pooling sum)
    k_dense<64, 32, 32, 64, 64, 64, 4, 32, 1, 0, 1><<<DENSE_GRID, 256, 0, stream>>>(
        T2, lw2, T1, lw2 + 64 * 64, lb2, X3F, N);

    // pool + post MLP
    k_pool<<<(N + 2047) / 2048, 256, 0, stream>>>(X3F, batch, gbuf, N);
    k_post1<<<(BC * 64 + 255) / 256, 256, 0, stream>>>(gbuf, cf, ncfg, pw1, pb1, zp, BC, B);
    k_post2<<<(BC + 3) / 4, 256, 0, stream>>>(zp, pw2, pb2, (float*)d_out, BC);
}

// Round 3
// 1034.443 us; speedup vs baseline: 1.6749x; 1.6499x over previous
//
#include <hip/hip_runtime.h>
#include <cstdint>
#include <cstddef>

// ---------------------------------------------------------------------------
// LateJoinSAGE round 3: MFMA (16x16x32 bf16) for all dense layers.
// Node features bf16 (layer0 padded 148->160). Weights pre-packed per launch
// into B-fragment order. Dense epilogue fuses bias + L2norm/lrelu + store.
// Aggregation (CSR gather mean) unchanged from round 2.
// ---------------------------------------------------------------------------

#define LRELU(v) ((v) > 0.f ? (v) : 0.01f * (v))

constexpr int SCAN_BS = 512;

typedef __attribute__((ext_vector_type(8))) short bf16x8;
typedef __attribute__((ext_vector_type(4))) float f32x4;

union U4B8 {
    uint4 u;
    bf16x8 b;
};

__device__ inline unsigned bf16_rn(float x) {
    unsigned u = __float_as_uint(x);
    return (u + 0x7fffu + ((u >> 16) & 1u)) >> 16;
}
__device__ inline unsigned pack2(float lo, float hi) {
    return bf16_rn(lo) | (bf16_rn(hi) << 16);
}
__device__ inline float2 up2(unsigned v) {
    return make_float2(__uint_as_float(v << 16), __uint_as_float(v & 0xffff0000u));
}

// ---------------- x0 concat -> bf16 padded stride 160 (80 uints) -----------
__global__ void k_concat(const float* __restrict__ nf, const int* __restrict__ opc,
                         const float* __restrict__ emb, unsigned* __restrict__ x0,
                         int n) {
    int idx = blockIdx.x * 256 + threadIdx.x;
    if (idx >= n * 80) return;
    int node = idx / 80;
    int u = idx - node * 80;
    int f0 = 2 * u, f1 = 2 * u + 1;
    float v0 = 0.f, v1 = 0.f;
    if (f0 < 140) v0 = nf[(size_t)node * 140 + f0];
    else if (f0 < 148) v0 = emb[opc[node] * 8 + (f0 - 140)];
    if (f1 < 140) v1 = nf[(size_t)node * 140 + f1];
    else if (f1 < 148) v1 = emb[opc[node] * 8 + (f1 - 140)];
    x0[idx] = pack2(v0, v1);
}

// ---------------- CSR build ----------------
__global__ void k_deg(const int* __restrict__ ei, int* __restrict__ deg, int E) {
    int e = blockIdx.x * 256 + threadIdx.x;
    if (e >= E) return;
    int a = ei[2 * e], b = ei[2 * e + 1];
    atomicAdd(&deg[b], 1);
    atomicAdd(&deg[a], 1);
}

__global__ void k_scan1(const int* __restrict__ deg, int* __restrict__ excl,
                        int* __restrict__ partials, int n) {
    __shared__ int sm[SCAN_BS];
    int t = threadIdx.x;
    int i = blockIdx.x * SCAN_BS + t;
    int v = (i < n) ? deg[i] : 0;
    sm[t] = v;
    __syncthreads();
    for (int off = 1; off < SCAN_BS; off <<= 1) {
        int tmp = 0;
        if (t >= off) tmp = sm[t - off];
        __syncthreads();
        sm[t] += tmp;
        __syncthreads();
    }
    if (i < n) excl[i] = sm[t] - v;
    if (t == SCAN_BS - 1) partials[blockIdx.x] = sm[t];
}

__global__ void k_scan2(int* __restrict__ p, int n) {
    __shared__ int sm[SCAN_BS];
    int t = threadIdx.x;
    int v = (t < n) ? p[t] : 0;
    sm[t] = v;
    __syncthreads();
    for (int off = 1; off < SCAN_BS; off <<= 1) {
        int tmp = 0;
        if (t >= off) tmp = sm[t - off];
        __syncthreads();
        sm[t] += tmp;
        __syncthreads();
    }
    if (t < n) p[t] = sm[t] - v;
}

__global__ void k_scan3(int* __restrict__ rp, const int* __restrict__ partials,
                        const int* __restrict__ deg, float* __restrict__ invd,
                        int n, int total) {
    int i = blockIdx.x * SCAN_BS + threadIdx.x;
    if (i == 0) rp[n] = total;
    if (i >= n) return;
    rp[i] += partials[blockIdx.x];
    invd[i] = 1.0f / fmaxf((float)deg[i], 1.0f);
}

__global__ void k_fill(const int* __restrict__ ei, const int* __restrict__ rp,
                       int* __restrict__ fill, int* __restrict__ csr, int E) {
    int e = blockIdx.x * 256 + threadIdx.x;
    if (e >= E) return;
    int a = ei[2 * e], b = ei[2 * e + 1];
    int p1 = rp[b] + atomicAdd(&fill[b], 1);
    csr[p1] = a;
    int p2 = rp[a] + atomicAdd(&fill[a], 1);
    csr[p2] = b;
}

// ---------------- layer-0 aggregation: 160 bf16 / row (80 uints) -----------
__global__ __launch_bounds__(256) void k_agg160(
    const unsigned* __restrict__ x, const int* __restrict__ rp,
    const int* __restrict__ csr, const float* __restrict__ invd,
    unsigned* __restrict__ agg, int n) {
    int wave = threadIdx.x >> 6;
    int lane = threadIdx.x & 63;
    int node = blockIdx.x * 4 + wave;
    if (node >= n) return;
    float a0 = 0.f, a1 = 0.f, e0 = 0.f, e1 = 0.f;
    int s = rp[node], e2 = rp[node + 1];
    int q = lane >> 4;
    int pe = lane & 15;
    int j = s;
    for (; j + 4 <= e2; j += 4) {
        int u0 = csr[j], u1 = csr[j + 1], u2 = csr[j + 2], u3 = csr[j + 3];
        float2 v0 = up2(x[(size_t)u0 * 80 + lane]);
        float2 v1 = up2(x[(size_t)u1 * 80 + lane]);
        float2 v2 = up2(x[(size_t)u2 * 80 + lane]);
        float2 v3 = up2(x[(size_t)u3 * 80 + lane]);
        a0 += (v0.x + v1.x) + (v2.x + v3.x);
        a1 += (v0.y + v1.y) + (v2.y + v3.y);
        int ue = (q == 0) ? u0 : (q == 1) ? u1 : (q == 2) ? u2 : u3;
        float2 ve = up2(x[(size_t)ue * 80 + 64 + pe]);
        e0 += ve.x;
        e1 += ve.y;
    }
    for (; j < e2; j++) {
        int u = csr[j];
        float2 v = up2(x[(size_t)u * 80 + lane]);
        a0 += v.x;
        a1 += v.y;
        if (lane < 16) {
            float2 ve = up2(x[(size_t)u * 80 + 64 + lane]);
            e0 += ve.x;
            e1 += ve.y;
        }
    }
    e0 += __shfl_xor(e0, 16, 64);
    e1 += __shfl_xor(e1, 16, 64);
    e0 += __shfl_xor(e0, 32, 64);
    e1 += __shfl_xor(e1, 32, 64);
    float iv = invd[node];
    agg[(size_t)node * 80 + lane] = pack2(a0 * iv, a1 * iv);
    if (lane < 16) agg[(size_t)node * 80 + 64 + lane] = pack2(e0 * iv, e1 * iv);
}

// ---------------- 64-dim aggregation: 2 neighbors per wave pass ------------
__global__ __launch_bounds__(256) void k_agg64(
    const unsigned* __restrict__ x, const int* __restrict__ rp,
    const int* __restrict__ csr, const float* __restrict__ invd,
    unsigned* __restrict__ agg, int n) {
    int wave = threadIdx.x >> 6;
    int lane = threadIdx.x & 63;
    int node = blockIdx.x * 4 + wave;
    if (node >= n) return;
    int p = lane & 31;
    int h = lane >> 5;
    float a0 = 0.f, a1 = 0.f;
    int s = rp[node], e2 = rp[node + 1];
    int j = s;
    for (; j + 8 <= e2; j += 8) {
        int u0 = csr[j + 0 + h];
        int u1 = csr[j + 2 + h];
        int u2 = csr[j + 4 + h];
        int u3 = csr[j + 6 + h];
        float2 v0 = up2(x[(size_t)u0 * 32 + p]);
        float2 v1 = up2(x[(size_t)u1 * 32 + p]);
        float2 v2 = up2(x[(size_t)u2 * 32 + p]);
        float2 v3 = up2(x[(size_t)u3 * 32 + p]);
        a0 += (v0.x + v1.x) + (v2.x + v3.x);
        a1 += (v0.y + v1.y) + (v2.y + v3.y);
    }
    for (; j < e2; j += 2) {
        int idx = j + h;
        if (idx < e2) {
            int u = csr[idx];
            float2 v = up2(x[(size_t)u * 32 + p]);
            a0 += v.x;
            a1 += v.y;
        }
    }
    a0 += __shfl_xor(a0, 32, 64);
    a1 += __shfl_xor(a1, 32, 64);
    if (lane < 32) {
        float iv = invd[node];
        agg[(size_t)node * 32 + p] = pack2(a0 * iv, a1 * iv);
    }
}

// ---------------- weight pre-pack into B-fragment order --------------------
// Wp uint4 index ((ct*KS + ks)*64 + lane) holds 8 bf16:
//   col = ct*16 + (lane&15), k = ks*32 + (lane>>4)*8 + j
//   k <  KSH*32 : W1[k][col]        (0 if k >= K1 or col >= C)
//   k >= KSH*32 : W2[k-KSH*32][col] (0 if k-KSH*32 >= K2 or col >= C)
template <int KS, int KSH, int CT, int C>
__global__ void k_prep(const float* __restrict__ W1, const float* __restrict__ W2,
                       int K1, int K2, uint4* __restrict__ Wp) {
    int idx = blockIdx.x * 256 + threadIdx.x;
    if (idx >= CT * KS * 64) return;
    int l = idx & 63;
    int ks = (idx >> 6) % KS;
    int ct = idx / (KS * 64);
    int col = ct * 16 + (l & 15);
    int kbase = ks * 32 + (l >> 4) * 8;
    unsigned short v[8];
#pragma unroll
    for (int j = 0; j < 8; j++) {
        int k = kbase + j;
        float f = 0.f;
        if (col < C) {
            if (k < KSH * 32) {
                if (k < K1) f = W1[(size_t)k * C + col];
            } else {
                int k2 = k - KSH * 32;
                if (k2 < K2) f = W2[(size_t)k2 * C + col];
            }
        }
        v[j] = (unsigned short)bf16_rn(f);
    }
    uint4 o;
    o.x = v[0] | ((unsigned)v[1] << 16);
    o.y = v[2] | ((unsigned)v[3] << 16);
    o.z = v[4] | ((unsigned)v[5] << 16);
    o.w = v[6] | ((unsigned)v[7] << 16);
    Wp[idx] = o;
}

// ---------------- MFMA GEMM: out = post([A|B] @ Wp + bias) -----------------
// A,B bf16 rows, stride KSH*32 elements (= KSH*4 uint4). 64 rows/block,
// wave w owns rows rb+w*16..+15 across all CT col-tiles. KS k-steps of 32.
// NORM: fused L2 row-normalize. ACT: leaky relu. OUTF: 1 -> f32 out.
template <int KS, int KSH, int CT, int C, int OST, int NORM, int ACT, int OUTF>
__global__ __launch_bounds__(256) void k_gemm(
    const uint4* __restrict__ A, const uint4* __restrict__ Bb,
    const uint4* __restrict__ Wp, const float* __restrict__ bias,
    void* __restrict__ outv, int n) {
    int l = threadIdx.x & 63;
    int wv = threadIdx.x >> 6;
    int rb = blockIdx.x * 64 + wv * 16;
    int rowA = rb + (l & 15);
    if (rowA >= n) rowA = n - 1;           // clamp; stores are guarded
    int koct = l >> 4;
    const int strideU = KSH * 4;           // uint4 per row
    size_t baseA = (size_t)rowA * strideU + koct;

    f32x4 acc[CT];
#pragma unroll
    for (int ct = 0; ct < CT; ct++) acc[ct] = (f32x4){0.f, 0.f, 0.f, 0.f};

#pragma unroll
    for (int ks = 0; ks < KS; ks++) {
        U4B8 a;
        a.u = (ks < KSH) ? A[baseA + ks * 4] : Bb[baseA + (ks - KSH) * 4];
#pragma unroll
        for (int ct = 0; ct < CT; ct++) {
            U4B8 b;
            b.u = Wp[(ct * KS + ks) * 64 + l];
            acc[ct] = __builtin_amdgcn_mfma_f32_16x16x32_bf16(a.b, b.b, acc[ct], 0, 0, 0);
        }
    }

    int cid = l & 15;
    int grp = l >> 4;
#pragma unroll
    for (int ct = 0; ct < CT; ct++) {
        int col = ct * 16 + cid;
        float bv = (col < C) ? bias[col] : 0.f;
#pragma unroll
        for (int r = 0; r < 4; r++) acc[ct][r] += bv;
    }

    if (NORM) {
        float ss[4];
#pragma unroll
        for (int r = 0; r < 4; r++) {
            ss[r] = 0.f;
#pragma unroll
            for (int ct = 0; ct < CT; ct++) ss[r] += acc[ct][r] * acc[ct][r];
        }
#pragma unroll
        for (int off = 1; off < 16; off <<= 1) {
#pragma unroll
            for (int r = 0; r < 4; r++) ss[r] += __shfl_xor(ss[r], off, 64);
        }
#pragma unroll
        for (int r = 0; r < 4; r++) {
            float sc = 1.0f / fmaxf(sqrtf(ss[r]), 1e-12f);
#pragma unroll
            for (int ct = 0; ct < CT; ct++) acc[ct][r] *= sc;
        }
    }

    if (ACT) {
#pragma unroll
        for (int ct = 0; ct < CT; ct++)
#pragma unroll
            for (int r = 0; r < 4; r++) acc[ct][r] = LRELU(acc[ct][r]);
    }

#pragma unroll
    for (int r = 0; r < 4; r++) {
        int row = rb + grp * 4 + r;
        if (row >= n) continue;
        if (OUTF) {
            float* o = (float*)outv;
#pragma unroll
            for (int ct = 0; ct < CT; ct++) {
                int col = ct * 16 + cid;
                if (col < OST) o[(size_t)row * OST + col] = acc[ct][r];
            }
        } else {
            unsigned short* o = (unsigned short*)outv;
#pragma unroll
            for (int ct = 0; ct < CT; ct++) {
                int col = ct * 16 + cid;
                if (col < OST) o[(size_t)row * OST + col] = (unsigned short)bf16_rn(acc[ct][r]);
            }
        }
    }
}

// ---------------- global add-pool (f32 input) ----------------
__global__ void k_pool(const float* __restrict__ x, const int* __restrict__ batch,
                       float* __restrict__ g, int n) {
    constexpr int CHUNK = 512;
    int c = threadIdx.x & 63;
    int sub = threadIdx.x >> 6;
    int n0 = (blockIdx.x * 4 + sub) * CHUNK;
    float acc = 0.f;
    int cur = -1;
    for (int i = 0; i < CHUNK; i++) {
        int node = n0 + i;
        if (node >= n) break;
        int bg = batch[node];
        if (bg != cur) {
            if (cur >= 0) atomicAdd(&g[cur * 64 + c], acc);
            cur = bg;
            acc = 0.f;
        }
        acc += x[(size_t)node * 64 + c];
    }
    if (cur >= 0) atomicAdd(&g[cur * 64 + c], acc);
}

// ---------------- post MLP ----------------
__global__ void k_post1(const float* __restrict__ g, const float* __restrict__ cf,
                        const int* __restrict__ ncfg, const float* __restrict__ w1,
                        const float* __restrict__ b1, float* __restrict__ z,
                        int BC, int B) {
    int idx = blockIdx.x * 256 + threadIdx.x;
    if (idx >= BC * 64) return;
    int row = idx >> 6, c = idx & 63;
    int gsum = 0, gid = B - 1;
    for (int b2 = 0; b2 < B; b2++) {
        int ns = ncfg[b2];
        if (row < gsum + ns) { gid = b2; break; }
        gsum += ns;
    }
    float acc = b1[c];
#pragma unroll 4
    for (int k = 0; k < 64; k++) acc += g[gid * 64 + k] * w1[k * 64 + c];
#pragma unroll 4
    for (int k = 0; k < 24; k++) acc += cf[(size_t)row * 24 + k] * w1[(64 + k) * 64 + c];
    z[idx] = LRELU(acc);
}

__global__ void k_post2(const float* __restrict__ z, const float* __restrict__ w2,
                        const float* __restrict__ b2, float* __restrict__ out, int BC) {
    int row = blockIdx.x * 4 + (threadIdx.x >> 6);
    if (row >= BC) return;
    int c = threadIdx.x & 63;
    float v = z[(size_t)row * 64 + c] * w2[c];
#pragma unroll
    for (int off = 32; off > 0; off >>= 1) v += __shfl_xor(v, off, 64);
    if (c == 0) out[row] = v + b2[0];
}

// ---------------------------------------------------------------------------
extern "C" void kernel_launch(void* const* d_in, const int* in_sizes, int n_in,
                              void* d_out, int out_size, void* d_ws, size_t ws_size,
                              hipStream_t stream) {
    const float* node_feat = (const float*)d_in[0];
    const int*   opcode    = (const int*)d_in[1];
    const int*   ei        = (const int*)d_in[2];
    const float* cf        = (const float*)d_in[3];
    const int*   ncfg      = (const int*)d_in[4];
    const int*   batch     = (const int*)d_in[5];
    const float* emb       = (const float*)d_in[6];
    const float* wl0 = (const float*)d_in[7];
    const float* bl0 = (const float*)d_in[8];
    const float* wr0 = (const float*)d_in[9];
    const float* lw0 = (const float*)d_in[10];
    const float* lb0 = (const float*)d_in[11];
    const float* wl1 = (const float*)d_in[12];
    const float* bl1 = (const float*)d_in[13];
    const float* wr1 = (const float*)d_in[14];
    const float* lw1 = (const float*)d_in[15];
    const float* lb1 = (const float*)d_in[16];
    const float* wl2 = (const float*)d_in[17];
    const float* bl2 = (const float*)d_in[18];
    const float* wr2 = (const float*)d_in[19];
    const float* lw2 = (const float*)d_in[20];
    const float* lb2 = (const float*)d_in[21];
    const float* pw1 = (const float*)d_in[22];
    const float* pb1 = (const float*)d_in[23];
    const float* pw2 = (const float*)d_in[24];
    const float* pb2 = (const float*)d_in[25];

    const int N  = in_sizes[0] / 140;
    const int E  = in_sizes[2] / 2;
    const int B  = in_sizes[4];
    const int BC = in_sizes[3] / 24;

    char* w = (char*)d_ws;
    auto alloc = [&](size_t bytes) {
        void* p = (void*)w;
        w += (bytes + 255) & ~(size_t)255;
        return p;
    };
    int*      deg      = (int*)alloc((size_t)N * 4);
    int*      rp       = (int*)alloc((size_t)(N + 1) * 4);
    int*      fill     = (int*)alloc((size_t)N * 4);
    int*      partials = (int*)alloc(1024 * 4);
    float*    invd     = (float*)alloc((size_t)N * 4);
    int*      csr      = (int*)alloc((size_t)2 * E * 4);
    unsigned* X0       = (unsigned*)alloc((size_t)N * 80 * 4);   // bf16, stride 160
    unsigned* AG0      = (unsigned*)alloc((size_t)N * 80 * 4);
    unsigned* H0       = (unsigned*)alloc((size_t)N * 80 * 4);
    unsigned* T0       = (unsigned*)alloc((size_t)N * 32 * 4);   // bf16, stride 64
    unsigned* T1       = (unsigned*)alloc((size_t)N * 32 * 4);
    unsigned* T2       = (unsigned*)alloc((size_t)N * 32 * 4);
    float*    X3F      = (float*)alloc((size_t)N * 64 * 4);      // final x, f32
    float*    gbuf     = (float*)alloc((size_t)B * 64 * 4);
    float*    zp       = (float*)alloc((size_t)BC * 64 * 4);
    uint4*    Wp0h     = (uint4*)alloc((size_t)10 * 10 * 64 * 16);
    uint4*    Wp0l     = (uint4*)alloc((size_t)4 * 10 * 64 * 16);
    uint4*    Wp1h     = (uint4*)alloc((size_t)4 * 4 * 64 * 16);
    uint4*    Wp1l     = (uint4*)alloc((size_t)4 * 4 * 64 * 16);
    uint4*    Wp2h     = (uint4*)alloc((size_t)4 * 4 * 64 * 16);
    uint4*    Wp2l     = (uint4*)alloc((size_t)4 * 4 * 64 * 16);
    (void)ws_size; (void)n_in; (void)out_size;

    hipMemsetAsync(deg, 0, (size_t)N * 4, stream);
    hipMemsetAsync(fill, 0, (size_t)N * 4, stream);
    hipMemsetAsync(gbuf, 0, (size_t)B * 64 * 4, stream);

    const int NB1 = (N + SCAN_BS - 1) / SCAN_BS;

    // weight pre-pack (tiny)
    k_prep<10, 5, 10, 148><<<(6400 + 255) / 256, 256, 0, stream>>>(wl0, wr0, 148, 148, Wp0h);
    k_prep<10, 5, 4, 64><<<(2560 + 255) / 256, 256, 0, stream>>>(lw0, lw0 + 148 * 64, 148, 148, Wp0l);
    k_prep<4, 2, 4, 64><<<4, 256, 0, stream>>>(wl1, wr1, 64, 64, Wp1h);
    k_prep<4, 2, 4, 64><<<4, 256, 0, stream>>>(lw1, lw1 + 64 * 64, 64, 64, Wp1l);
    k_prep<4, 2, 4, 64><<<4, 256, 0, stream>>>(wl2, wr2, 64, 64, Wp2h);
    k_prep<4, 2, 4, 64><<<4, 256, 0, stream>>>(lw2, lw2 + 64 * 64, 64, 64, Wp2l);

    k_concat<<<(N * 80 + 255) / 256, 256, 0, stream>>>(node_feat, opcode, emb, X0, N);
    k_deg<<<(E + 255) / 256, 256, 0, stream>>>(ei, deg, E);
    k_scan1<<<NB1, SCAN_BS, 0, stream>>>(deg, rp, partials, N);
    k_scan2<<<1, SCAN_BS, 0, stream>>>(partials, NB1);
    k_scan3<<<NB1, SCAN_BS, 0, stream>>>(rp, partials, deg, invd, N, 2 * E);
    k_fill<<<(E + 255) / 256, 256, 0, stream>>>(ei, rp, fill, csr, E);

    const int AGG_GRID  = (N + 3) / 4;
    const int GEMM_GRID = (N + 63) / 64;

    // ---- layer 0 ----
    k_agg160<<<AGG_GRID, 256, 0, stream>>>(X0, rp, csr, invd, AG0, N);
    // h0 = norm(agg@wl0 + x0@wr0 + bl0) -> H0 (bf16, stride 160)
    k_gemm<10, 5, 10, 148, 160, 1, 0, 0><<<GEMM_GRID, 256, 0, stream>>>(
        (const uint4*)AG0, (const uint4*)X0, Wp0h, bl0, H0, N);
    // x1 = lrelu([h0,x0]@lw0 + lb0) -> T0 (bf16, stride 64)
    k_gemm<10, 5, 4, 64, 64, 0, 1, 0><<<GEMM_GRID, 256, 0, stream>>>(
        (const uint4*)H0, (const uint4*)X0, Wp0l, lb0, T0, N);

    // ---- layer 1 ----
    k_agg64<<<AGG_GRID, 256, 0, stream>>>(T0, rp, csr, invd, T1, N);
    k_gemm<4, 2, 4, 64, 64, 1, 0, 0><<<GEMM_GRID, 256, 0, stream>>>(
        (const uint4*)T1, (const uint4*)T0, Wp1h, bl1, T2, N);
    k_gemm<4, 2, 4, 64, 64, 0, 1, 0><<<GEMM_GRID, 256, 0, stream>>>(
        (const uint4*)T2, (const uint4*)T0, Wp1l, lb1, T1, N);

    // ---- layer 2 ----
    k_agg64<<<AGG_GRID, 256, 0, stream>>>(T1, rp, csr, invd, T0, N);
    k_gemm<4, 2, 4, 64, 64, 1, 0, 0><<<GEMM_GRID, 256, 0, stream>>>(
        (const uint4*)T0, (const uint4*)T1, Wp2h, bl2, T2, N);
    // x3 = lrelu([h2,x2]@lw2 + lb2) -> f32 (pool accuracy)
    k_gemm<4, 2, 4, 64, 64, 0, 1, 1><<<GEMM_GRID, 256, 0, stream>>>(
        (const uint4*)T2, (const uint4*)T1, Wp2l, lb2, X3F, N);

    // pool + post MLP
    k_pool<<<(N + 2047) / 2048, 256, 0, stream>>>(X3F, batch, gbuf, N);
    k_post1<<<(BC * 64 + 255) / 256, 256, 0, stream>>>(gbuf, cf, ncfg, pw1, pb1, zp, BC, B);
    k_post2<<<(BC + 3) / 4, 256, 0, stream>>>(zp, pw2, pb2, (float*)d_out, BC);
}

// Round 4
// 819.815 us; speedup vs baseline: 2.1134x; 1.2618x over previous
//
#include <hip/hip_runtime.h>
#include <cstdint>
#include <cstddef>

// ---------------------------------------------------------------------------
// LateJoinSAGE round 4: round 3 (MFMA dense, bf16 features) + parallel pool.
// k_pool was 2%-occupancy latency-bound (275us); now wave-per-64-rows
// coalesced with LDS combine + ~2 atomics/block.
// ---------------------------------------------------------------------------

#define LRELU(v) ((v) > 0.f ? (v) : 0.01f * (v))

constexpr int SCAN_BS = 512;

typedef __attribute__((ext_vector_type(8))) short bf16x8;
typedef __attribute__((ext_vector_type(4))) float f32x4;

union U4B8 {
    uint4 u;
    bf16x8 b;
};

__device__ inline unsigned bf16_rn(float x) {
    unsigned u = __float_as_uint(x);
    return (u + 0x7fffu + ((u >> 16) & 1u)) >> 16;
}
__device__ inline unsigned pack2(float lo, float hi) {
    return bf16_rn(lo) | (bf16_rn(hi) << 16);
}
__device__ inline float2 up2(unsigned v) {
    return make_float2(__uint_as_float(v << 16), __uint_as_float(v & 0xffff0000u));
}

// ---------------- x0 concat -> bf16 padded stride 160 (80 uints) -----------
__global__ void k_concat(const float* __restrict__ nf, const int* __restrict__ opc,
                         const float* __restrict__ emb, unsigned* __restrict__ x0,
                         int n) {
    int idx = blockIdx.x * 256 + threadIdx.x;
    if (idx >= n * 80) return;
    int node = idx / 80;
    int u = idx - node * 80;
    int f0 = 2 * u, f1 = 2 * u + 1;
    float v0 = 0.f, v1 = 0.f;
    if (f0 < 140) v0 = nf[(size_t)node * 140 + f0];
    else if (f0 < 148) v0 = emb[opc[node] * 8 + (f0 - 140)];
    if (f1 < 140) v1 = nf[(size_t)node * 140 + f1];
    else if (f1 < 148) v1 = emb[opc[node] * 8 + (f1 - 140)];
    x0[idx] = pack2(v0, v1);
}

// ---------------- CSR build ----------------
__global__ void k_deg(const int* __restrict__ ei, int* __restrict__ deg, int E) {
    int e = blockIdx.x * 256 + threadIdx.x;
    if (e >= E) return;
    int a = ei[2 * e], b = ei[2 * e + 1];
    atomicAdd(&deg[b], 1);
    atomicAdd(&deg[a], 1);
}

__global__ void k_scan1(const int* __restrict__ deg, int* __restrict__ excl,
                        int* __restrict__ partials, int n) {
    __shared__ int sm[SCAN_BS];
    int t = threadIdx.x;
    int i = blockIdx.x * SCAN_BS + t;
    int v = (i < n) ? deg[i] : 0;
    sm[t] = v;
    __syncthreads();
    for (int off = 1; off < SCAN_BS; off <<= 1) {
        int tmp = 0;
        if (t >= off) tmp = sm[t - off];
        __syncthreads();
        sm[t] += tmp;
        __syncthreads();
    }
    if (i < n) excl[i] = sm[t] - v;
    if (t == SCAN_BS - 1) partials[blockIdx.x] = sm[t];
}

__global__ void k_scan2(int* __restrict__ p, int n) {
    __shared__ int sm[SCAN_BS];
    int t = threadIdx.x;
    int v = (t < n) ? p[t] : 0;
    sm[t] = v;
    __syncthreads();
    for (int off = 1; off < SCAN_BS; off <<= 1) {
        int tmp = 0;
        if (t >= off) tmp = sm[t - off];
        __syncthreads();
        sm[t] += tmp;
        __syncthreads();
    }
    if (t < n) p[t] = sm[t] - v;
}

__global__ void k_scan3(int* __restrict__ rp, const int* __restrict__ partials,
                        const int* __restrict__ deg, float* __restrict__ invd,
                        int n, int total) {
    int i = blockIdx.x * SCAN_BS + threadIdx.x;
    if (i == 0) rp[n] = total;
    if (i >= n) return;
    rp[i] += partials[blockIdx.x];
    invd[i] = 1.0f / fmaxf((float)deg[i], 1.0f);
}

__global__ void k_fill(const int* __restrict__ ei, const int* __restrict__ rp,
                       int* __restrict__ fill, int* __restrict__ csr, int E) {
    int e = blockIdx.x * 256 + threadIdx.x;
    if (e >= E) return;
    int a = ei[2 * e], b = ei[2 * e + 1];
    int p1 = rp[b] + atomicAdd(&fill[b], 1);
    csr[p1] = a;
    int p2 = rp[a] + atomicAdd(&fill[a], 1);
    csr[p2] = b;
}

// ---------------- layer-0 aggregation: 160 bf16 / row (80 uints) -----------
__global__ __launch_bounds__(256) void k_agg160(
    const unsigned* __restrict__ x, const int* __restrict__ rp,
    const int* __restrict__ csr, const float* __restrict__ invd,
    unsigned* __restrict__ agg, int n) {
    int wave = threadIdx.x >> 6;
    int lane = threadIdx.x & 63;
    int node = blockIdx.x * 4 + wave;
    if (node >= n) return;
    float a0 = 0.f, a1 = 0.f, e0 = 0.f, e1 = 0.f;
    int s = rp[node], e2 = rp[node + 1];
    int q = lane >> 4;
    int pe = lane & 15;
    int j = s;
    for (; j + 4 <= e2; j += 4) {
        int u0 = csr[j], u1 = csr[j + 1], u2 = csr[j + 2], u3 = csr[j + 3];
        float2 v0 = up2(x[(size_t)u0 * 80 + lane]);
        float2 v1 = up2(x[(size_t)u1 * 80 + lane]);
        float2 v2 = up2(x[(size_t)u2 * 80 + lane]);
        float2 v3 = up2(x[(size_t)u3 * 80 + lane]);
        a0 += (v0.x + v1.x) + (v2.x + v3.x);
        a1 += (v0.y + v1.y) + (v2.y + v3.y);
        int ue = (q == 0) ? u0 : (q == 1) ? u1 : (q == 2) ? u2 : u3;
        float2 ve = up2(x[(size_t)ue * 80 + 64 + pe]);
        e0 += ve.x;
        e1 += ve.y;
    }
    for (; j < e2; j++) {
        int u = csr[j];
        float2 v = up2(x[(size_t)u * 80 + lane]);
        a0 += v.x;
        a1 += v.y;
        if (lane < 16) {
            float2 ve = up2(x[(size_t)u * 80 + 64 + lane]);
            e0 += ve.x;
            e1 += ve.y;
        }
    }
    e0 += __shfl_xor(e0, 16, 64);
    e1 += __shfl_xor(e1, 16, 64);
    e0 += __shfl_xor(e0, 32, 64);
    e1 += __shfl_xor(e1, 32, 64);
    float iv = invd[node];
    agg[(size_t)node * 80 + lane] = pack2(a0 * iv, a1 * iv);
    if (lane < 16) agg[(size_t)node * 80 + 64 + lane] = pack2(e0 * iv, e1 * iv);
}

// ---------------- 64-dim aggregation: 2 neighbors per wave pass ------------
__global__ __launch_bounds__(256) void k_agg64(
    const unsigned* __restrict__ x, const int* __restrict__ rp,
    const int* __restrict__ csr, const float* __restrict__ invd,
    unsigned* __restrict__ agg, int n) {
    int wave = threadIdx.x >> 6;
    int lane = threadIdx.x & 63;
    int node = blockIdx.x * 4 + wave;
    if (node >= n) return;
    int p = lane & 31;
    int h = lane >> 5;
    float a0 = 0.f, a1 = 0.f;
    int s = rp[node], e2 = rp[node + 1];
    int j = s;
    for (; j + 8 <= e2; j += 8) {
        int u0 = csr[j + 0 + h];
        int u1 = csr[j + 2 + h];
        int u2 = csr[j + 4 + h];
        int u3 = csr[j + 6 + h];
        float2 v0 = up2(x[(size_t)u0 * 32 + p]);
        float2 v1 = up2(x[(size_t)u1 * 32 + p]);
        float2 v2 = up2(x[(size_t)u2 * 32 + p]);
        float2 v3 = up2(x[(size_t)u3 * 32 + p]);
        a0 += (v0.x + v1.x) + (v2.x + v3.x);
        a1 += (v0.y + v1.y) + (v2.y + v3.y);
    }
    for (; j < e2; j += 2) {
        int idx = j + h;
        if (idx < e2) {
            int u = csr[idx];
            float2 v = up2(x[(size_t)u * 32 + p]);
            a0 += v.x;
            a1 += v.y;
        }
    }
    a0 += __shfl_xor(a0, 32, 64);
    a1 += __shfl_xor(a1, 32, 64);
    if (lane < 32) {
        float iv = invd[node];
        agg[(size_t)node * 32 + p] = pack2(a0 * iv, a1 * iv);
    }
}

// ---------------- weight pre-pack into B-fragment order --------------------
template <int KS, int KSH, int CT, int C>
__global__ void k_prep(const float* __restrict__ W1, const float* __restrict__ W2,
                       int K1, int K2, uint4* __restrict__ Wp) {
    int idx = blockIdx.x * 256 + threadIdx.x;
    if (idx >= CT * KS * 64) return;
    int l = idx & 63;
    int ks = (idx >> 6) % KS;
    int ct = idx / (KS * 64);
    int col = ct * 16 + (l & 15);
    int kbase = ks * 32 + (l >> 4) * 8;
    unsigned short v[8];
#pragma unroll
    for (int j = 0; j < 8; j++) {
        int k = kbase + j;
        float f = 0.f;
        if (col < C) {
            if (k < KSH * 32) {
                if (k < K1) f = W1[(size_t)k * C + col];
            } else {
                int k2 = k - KSH * 32;
                if (k2 < K2) f = W2[(size_t)k2 * C + col];
            }
        }
        v[j] = (unsigned short)bf16_rn(f);
    }
    uint4 o;
    o.x = v[0] | ((unsigned)v[1] << 16);
    o.y = v[2] | ((unsigned)v[3] << 16);
    o.z = v[4] | ((unsigned)v[5] << 16);
    o.w = v[6] | ((unsigned)v[7] << 16);
    Wp[idx] = o;
}

// ---------------- MFMA GEMM: out = post([A|B] @ Wp + bias) -----------------
template <int KS, int KSH, int CT, int C, int OST, int NORM, int ACT, int OUTF>
__global__ __launch_bounds__(256) void k_gemm(
    const uint4* __restrict__ A, const uint4* __restrict__ Bb,
    const uint4* __restrict__ Wp, const float* __restrict__ bias,
    void* __restrict__ outv, int n) {
    int l = threadIdx.x & 63;
    int wv = threadIdx.x >> 6;
    int rb = blockIdx.x * 64 + wv * 16;
    int rowA = rb + (l & 15);
    if (rowA >= n) rowA = n - 1;           // clamp; stores are guarded
    int koct = l >> 4;
    const int strideU = KSH * 4;           // uint4 per row
    size_t baseA = (size_t)rowA * strideU + koct;

    f32x4 acc[CT];
#pragma unroll
    for (int ct = 0; ct < CT; ct++) acc[ct] = (f32x4){0.f, 0.f, 0.f, 0.f};

#pragma unroll
    for (int ks = 0; ks < KS; ks++) {
        U4B8 a;
        a.u = (ks < KSH) ? A[baseA + ks * 4] : Bb[baseA + (ks - KSH) * 4];
#pragma unroll
        for (int ct = 0; ct < CT; ct++) {
            U4B8 b;
            b.u = Wp[(ct * KS + ks) * 64 + l];
            acc[ct] = __builtin_amdgcn_mfma_f32_16x16x32_bf16(a.b, b.b, acc[ct], 0, 0, 0);
        }
    }

    int cid = l & 15;
    int grp = l >> 4;
#pragma unroll
    for (int ct = 0; ct < CT; ct++) {
        int col = ct * 16 + cid;
        float bv = (col < C) ? bias[col] : 0.f;
#pragma unroll
        for (int r = 0; r < 4; r++) acc[ct][r] += bv;
    }

    if (NORM) {
        float ss[4];
#pragma unroll
        for (int r = 0; r < 4; r++) {
            ss[r] = 0.f;
#pragma unroll
            for (int ct = 0; ct < CT; ct++) ss[r] += acc[ct][r] * acc[ct][r];
        }
#pragma unroll
        for (int off = 1; off < 16; off <<= 1) {
#pragma unroll
            for (int r = 0; r < 4; r++) ss[r] += __shfl_xor(ss[r], off, 64);
        }
#pragma unroll
        for (int r = 0; r < 4; r++) {
            float sc = 1.0f / fmaxf(sqrtf(ss[r]), 1e-12f);
#pragma unroll
            for (int ct = 0; ct < CT; ct++) acc[ct][r] *= sc;
        }
    }

    if (ACT) {
#pragma unroll
        for (int ct = 0; ct < CT; ct++)
#pragma unroll
            for (int r = 0; r < 4; r++) acc[ct][r] = LRELU(acc[ct][r]);
    }

#pragma unroll
    for (int r = 0; r < 4; r++) {
        int row = rb + grp * 4 + r;
        if (row >= n) continue;
        if (OUTF) {
            float* o = (float*)outv;
#pragma unroll
            for (int ct = 0; ct < CT; ct++) {
                int col = ct * 16 + cid;
                if (col < OST) o[(size_t)row * OST + col] = acc[ct][r];
            }
        } else {
            unsigned short* o = (unsigned short*)outv;
#pragma unroll
            for (int ct = 0; ct < CT; ct++) {
                int col = ct * 16 + cid;
                if (col < OST) o[(size_t)row * OST + col] = (unsigned short)bf16_rn(acc[ct][r]);
            }
        }
    }
}

// ---------------- global add-pool: wave per 64 rows, coalesced -------------
// Assumes <=2 distinct batch ids per 64 contiguous nodes (graphs are N/B
// contiguous nodes each, N/B >> 64).
__global__ __launch_bounds__(256) void k_pool(const float* __restrict__ x,
                                              const int* __restrict__ batch,
                                              float* __restrict__ g, int n) {
    __shared__ float sm[8][64];
    __shared__ int sb[8];
    int lane = threadIdx.x & 63;
    int wv = threadIdx.x >> 6;
    int base = blockIdx.x * 256 + wv * 64;
    float a0 = 0.f, a1 = 0.f;
    int b0 = -1, b1 = -1;
    int end = (base + 64 < n) ? base + 64 : n;
    for (int row = base; row < end; row++) {
        int bg = batch[row];
        float v = x[(size_t)row * 64 + lane];
        if (b0 < 0) b0 = bg;
        if (bg == b0) a0 += v;
        else { if (b1 < 0) b1 = bg; a1 += v; }
    }
    sm[wv * 2 + 0][lane] = a0;
    sm[wv * 2 + 1][lane] = a1;
    if (lane == 0) {
        sb[wv * 2 + 0] = b0;
        sb[wv * 2 + 1] = b1;
    }
    __syncthreads();
    if (wv == 0) {
        float c0 = 0.f, c1 = 0.f;
        int d0 = -1, d1 = -1;
#pragma unroll
        for (int s = 0; s < 8; s++) {
            int bg = sb[s];
            if (bg < 0) continue;
            float v = sm[s][lane];
            if (d0 < 0) d0 = bg;
            if (bg == d0) c0 += v;
            else { if (d1 < 0) d1 = bg; c1 += v; }
        }
        if (d0 >= 0) atomicAdd(&g[d0 * 64 + lane], c0);
        if (d1 >= 0) atomicAdd(&g[d1 * 64 + lane], c1);
    }
}

// ---------------- post MLP ----------------
__global__ void k_post1(const float* __restrict__ g, const float* __restrict__ cf,
                        const int* __restrict__ ncfg, const float* __restrict__ w1,
                        const float* __restrict__ b1, float* __restrict__ z,
                        int BC, int B) {
    int idx = blockIdx.x * 256 + threadIdx.x;
    if (idx >= BC * 64) return;
    int row = idx >> 6, c = idx & 63;
    int gsum = 0, gid = B - 1;
    for (int b2 = 0; b2 < B; b2++) {
        int ns = ncfg[b2];
        if (row < gsum + ns) { gid = b2; break; }
        gsum += ns;
    }
    float acc = b1[c];
#pragma unroll 4
    for (int k = 0; k < 64; k++) acc += g[gid * 64 + k] * w1[k * 64 + c];
#pragma unroll 4
    for (int k = 0; k < 24; k++) acc += cf[(size_t)row * 24 + k] * w1[(64 + k) * 64 + c];
    z[idx] = LRELU(acc);
}

__global__ void k_post2(const float* __restrict__ z, const float* __restrict__ w2,
                        const float* __restrict__ b2, float* __restrict__ out, int BC) {
    int row = blockIdx.x * 4 + (threadIdx.x >> 6);
    if (row >= BC) return;
    int c = threadIdx.x & 63;
    float v = z[(size_t)row * 64 + c] * w2[c];
#pragma unroll
    for (int off = 32; off > 0; off >>= 1) v += __shfl_xor(v, off, 64);
    if (c == 0) out[row] = v + b2[0];
}

// ---------------------------------------------------------------------------
extern "C" void kernel_launch(void* const* d_in, const int* in_sizes, int n_in,
                              void* d_out, int out_size, void* d_ws, size_t ws_size,
                              hipStream_t stream) {
    const float* node_feat = (const float*)d_in[0];
    const int*   opcode    = (const int*)d_in[1];
    const int*   ei        = (const int*)d_in[2];
    const float* cf        = (const float*)d_in[3];
    const int*   ncfg      = (const int*)d_in[4];
    const int*   batch     = (const int*)d_in[5];
    const float* emb       = (const float*)d_in[6];
    const float* wl0 = (const float*)d_in[7];
    const float* bl0 = (const float*)d_in[8];
    const float* wr0 = (const float*)d_in[9];
    const float* lw0 = (const float*)d_in[10];
    const float* lb0 = (const float*)d_in[11];
    const float* wl1 = (const float*)d_in[12];
    const float* bl1 = (const float*)d_in[13];
    const float* wr1 = (const float*)d_in[14];
    const float* lw1 = (const float*)d_in[15];
    const float* lb1 = (const float*)d_in[16];
    const float* wl2 = (const float*)d_in[17];
    const float* bl2 = (const float*)d_in[18];
    const float* wr2 = (const float*)d_in[19];
    const float* lw2 = (const float*)d_in[20];
    const float* lb2 = (const float*)d_in[21];
    const float* pw1 = (const float*)d_in[22];
    const float* pb1 = (const float*)d_in[23];
    const float* pw2 = (const float*)d_in[24];
    const float* pb2 = (const float*)d_in[25];

    const int N  = in_sizes[0] / 140;
    const int E  = in_sizes[2] / 2;
    const int B  = in_sizes[4];
    const int BC = in_sizes[3] / 24;

    char* w = (char*)d_ws;
    auto alloc = [&](size_t bytes) {
        void* p = (void*)w;
        w += (bytes + 255) & ~(size_t)255;
        return p;
    };
    int*      deg      = (int*)alloc((size_t)N * 4);
    int*      rp       = (int*)alloc((size_t)(N + 1) * 4);
    int*      fill     = (int*)alloc((size_t)N * 4);
    int*      partials = (int*)alloc(1024 * 4);
    float*    invd     = (float*)alloc((size_t)N * 4);
    int*      csr      = (int*)alloc((size_t)2 * E * 4);
    unsigned* X0       = (unsigned*)alloc((size_t)N * 80 * 4);   // bf16, stride 160
    unsigned* AG0      = (unsigned*)alloc((size_t)N * 80 * 4);
    unsigned* H0       = (unsigned*)alloc((size_t)N * 80 * 4);
    unsigned* T0       = (unsigned*)alloc((size_t)N * 32 * 4);   // bf16, stride 64
    unsigned* T1       = (unsigned*)alloc((size_t)N * 32 * 4);
    unsigned* T2       = (unsigned*)alloc((size_t)N * 32 * 4);
    float*    X3F      = (float*)alloc((size_t)N * 64 * 4);      // final x, f32
    float*    gbuf     = (float*)alloc((size_t)B * 64 * 4);
    float*    zp       = (float*)alloc((size_t)BC * 64 * 4);
    uint4*    Wp0h     = (uint4*)alloc((size_t)10 * 10 * 64 * 16);
    uint4*    Wp0l     = (uint4*)alloc((size_t)4 * 10 * 64 * 16);
    uint4*    Wp1h     = (uint4*)alloc((size_t)4 * 4 * 64 * 16);
    uint4*    Wp1l     = (uint4*)alloc((size_t)4 * 4 * 64 * 16);
    uint4*    Wp2h     = (uint4*)alloc((size_t)4 * 4 * 64 * 16);
    uint4*    Wp2l     = (uint4*)alloc((size_t)4 * 4 * 64 * 16);
    (void)ws_size; (void)n_in; (void)out_size;

    hipMemsetAsync(deg, 0, (size_t)N * 4, stream);
    hipMemsetAsync(fill, 0, (size_t)N * 4, stream);
    hipMemsetAsync(gbuf, 0, (size_t)B * 64 * 4, stream);

    const int NB1 = (N + SCAN_BS - 1) / SCAN_BS;

    // weight pre-pack (tiny)
    k_prep<10, 5, 10, 148><<<(6400 + 255) / 256, 256, 0, stream>>>(wl0, wr0, 148, 148, Wp0h);
    k_prep<10, 5, 4, 64><<<(2560 + 255) / 256, 256, 0, stream>>>(lw0, lw0 + 148 * 64, 148, 148, Wp0l);
    k_prep<4, 2, 4, 64><<<4, 256, 0, stream>>>(wl1, wr1, 64, 64, Wp1h);
    k_prep<4, 2, 4, 64><<<4, 256, 0, stream>>>(lw1, lw1 + 64 * 64, 64, 64, Wp1l);
    k_prep<4, 2, 4, 64><<<4, 256, 0, stream>>>(wl2, wr2, 64, 64, Wp2h);
    k_prep<4, 2, 4, 64><<<4, 256, 0, stream>>>(lw2, lw2 + 64 * 64, 64, 64, Wp2l);

    k_concat<<<(N * 80 + 255) / 256, 256, 0, stream>>>(node_feat, opcode, emb, X0, N);
    k_deg<<<(E + 255) / 256, 256, 0, stream>>>(ei, deg, E);
    k_scan1<<<NB1, SCAN_BS, 0, stream>>>(deg, rp, partials, N);
    k_scan2<<<1, SCAN_BS, 0, stream>>>(partials, NB1);
    k_scan3<<<NB1, SCAN_BS, 0, stream>>>(rp, partials, deg, invd, N, 2 * E);
    k_fill<<<(E + 255) / 256, 256, 0, stream>>>(ei, rp, fill, csr, E);

    const int AGG_GRID  = (N + 3) / 4;
    const int GEMM_GRID = (N + 63) / 64;

    // ---- layer 0 ----
    k_agg160<<<AGG_GRID, 256, 0, stream>>>(X0, rp, csr, invd, AG0, N);
    k_gemm<10, 5, 10, 148, 160, 1, 0, 0><<<GEMM_GRID, 256, 0, stream>>>(
        (const uint4*)AG0, (const uint4*)X0, Wp0h, bl0, H0, N);
    k_gemm<10, 5, 4, 64, 64, 0, 1, 0><<<GEMM_GRID, 256, 0, stream>>>(
        (const uint4*)H0, (const uint4*)X0, Wp0l, lb0, T0, N);

    // ---- layer 1 ----
    k_agg64<<<AGG_GRID, 256, 0, stream>>>(T0, rp, csr, invd, T1, N);
    k_gemm<4, 2, 4, 64, 64, 1, 0, 0><<<GEMM_GRID, 256, 0, stream>>>(
        (const uint4*)T1, (const uint4*)T0, Wp1h, bl1, T2, N);
    k_gemm<4, 2, 4, 64, 64, 0, 1, 0><<<GEMM_GRID, 256, 0, stream>>>(
        (const uint4*)T2, (const uint4*)T0, Wp1l, lb1, T1, N);

    // ---- layer 2 ----
    k_agg64<<<AGG_GRID, 256, 0, stream>>>(T1, rp, csr, invd, T0, N);
    k_gemm<4, 2, 4, 64, 64, 1, 0, 0><<<GEMM_GRID, 256, 0, stream>>>(
        (const uint4*)T0, (const uint4*)T1, Wp2h, bl2, T2, N);
    k_gemm<4, 2, 4, 64, 64, 0, 1, 1><<<GEMM_GRID, 256, 0, stream>>>(
        (const uint4*)T2, (const uint4*)T1, Wp2l, lb2, X3F, N);

    // pool + post MLP
    k_pool<<<(N + 255) / 256, 256, 0, stream>>>(X3F, batch, gbuf, N);
    k_post1<<<(BC * 64 + 255) / 256, 256, 0, stream>>>(gbuf, cf, ncfg, pw1, pb1, zp, BC, B);
    k_post2<<<(BC + 3) / 4, 256, 0, stream>>>(zp, pw2, pb2, (float*)d_out, BC);
}

// Round 5
// 587.120 us; speedup vs baseline: 2.9511x; 1.3963x over previous
//
#include <hip/hip_runtime.h>
#include <cstdint>
#include <cstddef>

// ---------------------------------------------------------------------------
// LateJoinSAGE round 5: round 4 (MFMA dense, bf16 features, parallel pool)
// + bucketed CSR build replacing deg/scan/fill (k_fill had 16x write
// amplification from random 4B scatter: 197MB HBM writes for a 12.8MB array).
// Bucket = dst>>7 (128 nodes). Sort-by-bucket in LDS, coalesced flush,
// per-bucket finalize emits rp/csr/invd with fully coalesced writes.
// ---------------------------------------------------------------------------

#define LRELU(v) ((v) > 0.f ? (v) : 0.01f * (v))

typedef __attribute__((ext_vector_type(8))) short bf16x8;
typedef __attribute__((ext_vector_type(4))) float f32x4;

union U4B8 {
    uint4 u;
    bf16x8 b;
};

__device__ inline unsigned bf16_rn(float x) {
    unsigned u = __float_as_uint(x);
    return (u + 0x7fffu + ((u >> 16) & 1u)) >> 16;
}
__device__ inline unsigned pack2(float lo, float hi) {
    return bf16_rn(lo) | (bf16_rn(hi) << 16);
}
__device__ inline float2 up2(unsigned v) {
    return make_float2(__uint_as_float(v << 16), __uint_as_float(v & 0xffff0000u));
}

// ---------------- x0 concat -> bf16 padded stride 160 (80 uints) -----------
__global__ void k_concat(const float* __restrict__ nf, const int* __restrict__ opc,
                         const float* __restrict__ emb, unsigned* __restrict__ x0,
                         int n) {
    int idx = blockIdx.x * 256 + threadIdx.x;
    if (idx >= n * 80) return;
    int node = idx / 80;
    int u = idx - node * 80;
    int f0 = 2 * u, f1 = 2 * u + 1;
    float v0 = 0.f, v1 = 0.f;
    if (f0 < 140) v0 = nf[(size_t)node * 140 + f0];
    else if (f0 < 148) v0 = emb[opc[node] * 8 + (f0 - 140)];
    if (f1 < 140) v1 = nf[(size_t)node * 140 + f1];
    else if (f1 < 148) v1 = emb[opc[node] * 8 + (f1 - 140)];
    x0[idx] = pack2(v0, v1);
}

// ---------------- bucketed CSR build ----------------
// bucket(node) = node >> 7 (128 nodes per bucket), NBUCK = ceil(N/128) <= 1024.

__global__ __launch_bounds__(256) void k_bh(const int* __restrict__ ei, int E,
                                            int NBUCK, int* __restrict__ bcnt) {
    __shared__ int h[1024];
    int t = threadIdx.x;
    for (int i = t; i < 1024; i += 256) h[i] = 0;
    __syncthreads();
    int e0 = blockIdx.x * 4096, e1 = min(E, e0 + 4096);
    for (int e = e0 + t; e < e1; e += 256) {
        int a = ei[2 * e], b = ei[2 * e + 1];
        atomicAdd(&h[b >> 7], 1);
        atomicAdd(&h[a >> 7], 1);
    }
    __syncthreads();
    for (int i = t; i < NBUCK; i += 256)
        if (h[i]) atomicAdd(&bcnt[i], h[i]);
}

__global__ void k_bscan(const int* __restrict__ bcnt, int NBUCK,
                        int* __restrict__ bo, int* __restrict__ bfill) {
    __shared__ int sm[1024];
    int t = threadIdx.x;
    int v = (t < NBUCK) ? bcnt[t] : 0;
    sm[t] = v;
    __syncthreads();
    for (int off = 1; off < 1024; off <<= 1) {
        int u = 0;
        if (t >= off) u = sm[t - off];
        __syncthreads();
        sm[t] += u;
        __syncthreads();
    }
    if (t < NBUCK) {
        int ex = sm[t] - v;
        bo[t] = ex;
        bfill[t] = ex;
    }
    if (t == NBUCK - 1) bo[NBUCK] = sm[t];
}

__global__ __launch_bounds__(256) void k_bscatter(const int* __restrict__ ei, int E,
                                                  int* __restrict__ bfill,
                                                  uint2* __restrict__ pairs) {
    __shared__ int hist[1024], lbo[1024], gb[1024], cur[1024];
    __shared__ int wsum[4];
    __shared__ int stageD[8192];
    __shared__ int stageS[8192];
    int t = threadIdx.x;
    for (int i = t; i < 1024; i += 256) hist[i] = 0;
    __syncthreads();
    int e0 = blockIdx.x * 4096, e1 = min(E, e0 + 4096);
    for (int e = e0 + t; e < e1; e += 256) {
        int a = ei[2 * e], b = ei[2 * e + 1];
        atomicAdd(&hist[b >> 7], 1);
        atomicAdd(&hist[a >> 7], 1);
    }
    __syncthreads();
    // exclusive scan of hist[1024] (4 buckets per thread) + reserve global space
    int b4 = t * 4;
    int c0 = hist[b4], c1 = hist[b4 + 1], c2 = hist[b4 + 2], c3 = hist[b4 + 3];
    int ms = c0 + c1 + c2 + c3;
    int lane = t & 63, wv = t >> 6;
    int v = ms;
#pragma unroll
    for (int off = 1; off < 64; off <<= 1) {
        int u = __shfl_up(v, off, 64);
        if (lane >= off) v += u;
    }
    if (lane == 63) wsum[wv] = v;
    __syncthreads();
    int wb = 0;
    for (int i = 0; i < wv; i++) wb += wsum[i];
    int ex = wb + v - ms;
    lbo[b4] = ex;
    lbo[b4 + 1] = ex + c0;
    lbo[b4 + 2] = ex + c0 + c1;
    lbo[b4 + 3] = ex + c0 + c1 + c2;
    if (c0) gb[b4 + 0] = atomicAdd(&bfill[b4 + 0], c0);
    if (c1) gb[b4 + 1] = atomicAdd(&bfill[b4 + 1], c1);
    if (c2) gb[b4 + 2] = atomicAdd(&bfill[b4 + 2], c2);
    if (c3) gb[b4 + 3] = atomicAdd(&bfill[b4 + 3], c3);
    cur[b4] = 0;
    cur[b4 + 1] = 0;
    cur[b4 + 2] = 0;
    cur[b4 + 3] = 0;
    __syncthreads();
    // stage entries bucket-sorted in LDS
    for (int e = e0 + t; e < e1; e += 256) {
        int a = ei[2 * e], b = ei[2 * e + 1];
        int bk = b >> 7;
        int r = atomicAdd(&cur[bk], 1);
        int p = lbo[bk] + r;
        stageD[p] = b;
        stageS[p] = a;
        bk = a >> 7;
        r = atomicAdd(&cur[bk], 1);
        p = lbo[bk] + r;
        stageD[p] = a;
        stageS[p] = b;
    }
    __syncthreads();
    // coalesced-ish flush: bucket runs are contiguous in stage and in pairs
    int tot = 2 * (e1 - e0);
    for (int i = t; i < tot; i += 256) {
        int d = stageD[i];
        int bk = d >> 7;
        pairs[gb[bk] + (i - lbo[bk])] = make_uint2((unsigned)d, (unsigned)stageS[i]);
    }
}

__global__ __launch_bounds__(256) void k_bfinal(const uint2* __restrict__ pairs,
                                                const int* __restrict__ bo,
                                                int* __restrict__ rp,
                                                int* __restrict__ csr,
                                                float* __restrict__ invd,
                                                int N, int NBUCK) {
    __shared__ int hist[128], ls[128], cur[128];
    __shared__ unsigned outS[6144];
    int t = threadIdx.x;
    int bk = blockIdx.x;
    int n0 = bk << 7;
    int nn = min(128, N - n0);
    int base = bo[bk], cnt = bo[bk + 1] - base;
    if (t < 128) {
        hist[t] = 0;
        cur[t] = 0;
    }
    __syncthreads();
    for (int i = t; i < cnt; i += 256) atomicAdd(&hist[(int)pairs[base + i].x - n0], 1);
    __syncthreads();
    if (t == 0) {
        int run = 0;
        for (int i = 0; i < 128; i++) {
            ls[i] = run;
            run += hist[i];
        }
    }
    __syncthreads();
    if (t < nn) {
        int node = n0 + t;
        rp[node] = base + ls[t];
        invd[node] = 1.0f / fmaxf((float)hist[t], 1.0f);
    }
    if (bk == NBUCK - 1 && t == 0) rp[N] = base + cnt;
    bool inl = (cnt <= 6144);
    for (int i = t; i < cnt; i += 256) {
        uint2 pr = pairs[base + i];
        int loc = (int)pr.x - n0;
        int r = atomicAdd(&cur[loc], 1);
        int pos = ls[loc] + r;
        if (inl) outS[pos] = pr.y;
        else csr[base + pos] = (int)pr.y;
    }
    __syncthreads();
    if (inl)
        for (int i = t; i < cnt; i += 256) csr[base + i] = (int)outS[i];
}

// ---------------- layer-0 aggregation: 160 bf16 / row (80 uints) -----------
__global__ __launch_bounds__(256) void k_agg160(
    const unsigned* __restrict__ x, const int* __restrict__ rp,
    const int* __restrict__ csr, const float* __restrict__ invd,
    unsigned* __restrict__ agg, int n) {
    int wave = threadIdx.x >> 6;
    int lane = threadIdx.x & 63;
    int node = blockIdx.x * 4 + wave;
    if (node >= n) return;
    float a0 = 0.f, a1 = 0.f, e0 = 0.f, e1 = 0.f;
    int s = rp[node], e2 = rp[node + 1];
    int q = lane >> 4;
    int pe = lane & 15;
    int j = s;
    for (; j + 4 <= e2; j += 4) {
        int u0 = csr[j], u1 = csr[j + 1], u2 = csr[j + 2], u3 = csr[j + 3];
        float2 v0 = up2(x[(size_t)u0 * 80 + lane]);
        float2 v1 = up2(x[(size_t)u1 * 80 + lane]);
        float2 v2 = up2(x[(size_t)u2 * 80 + lane]);
        float2 v3 = up2(x[(size_t)u3 * 80 + lane]);
        a0 += (v0.x + v1.x) + (v2.x + v3.x);
        a1 += (v0.y + v1.y) + (v2.y + v3.y);
        int ue = (q == 0) ? u0 : (q == 1) ? u1 : (q == 2) ? u2 : u3;
        float2 ve = up2(x[(size_t)ue * 80 + 64 + pe]);
        e0 += ve.x;
        e1 += ve.y;
    }
    for (; j < e2; j++) {
        int u = csr[j];
        float2 v = up2(x[(size_t)u * 80 + lane]);
        a0 += v.x;
        a1 += v.y;
        if (lane < 16) {
            float2 ve = up2(x[(size_t)u * 80 + 64 + lane]);
            e0 += ve.x;
            e1 += ve.y;
        }
    }
    e0 += __shfl_xor(e0, 16, 64);
    e1 += __shfl_xor(e1, 16, 64);
    e0 += __shfl_xor(e0, 32, 64);
    e1 += __shfl_xor(e1, 32, 64);
    float iv = invd[node];
    agg[(size_t)node * 80 + lane] = pack2(a0 * iv, a1 * iv);
    if (lane < 16) agg[(size_t)node * 80 + 64 + lane] = pack2(e0 * iv, e1 * iv);
}

// ---------------- 64-dim aggregation: 2 neighbors per wave pass ------------
__global__ __launch_bounds__(256) void k_agg64(
    const unsigned* __restrict__ x, const int* __restrict__ rp,
    const int* __restrict__ csr, const float* __restrict__ invd,
    unsigned* __restrict__ agg, int n) {
    int wave = threadIdx.x >> 6;
    int lane = threadIdx.x & 63;
    int node = blockIdx.x * 4 + wave;
    if (node >= n) return;
    int p = lane & 31;
    int h = lane >> 5;
    float a0 = 0.f, a1 = 0.f;
    int s = rp[node], e2 = rp[node + 1];
    int j = s;
    for (; j + 8 <= e2; j += 8) {
        int u0 = csr[j + 0 + h];
        int u1 = csr[j + 2 + h];
        int u2 = csr[j + 4 + h];
        int u3 = csr[j + 6 + h];
        float2 v0 = up2(x[(size_t)u0 * 32 + p]);
        float2 v1 = up2(x[(size_t)u1 * 32 + p]);
        float2 v2 = up2(x[(size_t)u2 * 32 + p]);
        float2 v3 = up2(x[(size_t)u3 * 32 + p]);
        a0 += (v0.x + v1.x) + (v2.x + v3.x);
        a1 += (v0.y + v1.y) + (v2.y + v3.y);
    }
    for (; j < e2; j += 2) {
        int idx = j + h;
        if (idx < e2) {
            int u = csr[idx];
            float2 v = up2(x[(size_t)u * 32 + p]);
            a0 += v.x;
            a1 += v.y;
        }
    }
    a0 += __shfl_xor(a0, 32, 64);
    a1 += __shfl_xor(a1, 32, 64);
    if (lane < 32) {
        float iv = invd[node];
        agg[(size_t)node * 32 + p] = pack2(a0 * iv, a1 * iv);
    }
}

// ---------------- weight pre-pack into B-fragment order --------------------
template <int KS, int KSH, int CT, int C>
__global__ void k_prep(const float* __restrict__ W1, const float* __restrict__ W2,
                       int K1, int K2, uint4* __restrict__ Wp) {
    int idx = blockIdx.x * 256 + threadIdx.x;
    if (idx >= CT * KS * 64) return;
    int l = idx & 63;
    int ks = (idx >> 6) % KS;
    int ct = idx / (KS * 64);
    int col = ct * 16 + (l & 15);
    int kbase = ks * 32 + (l >> 4) * 8;
    unsigned short v[8];
#pragma unroll
    for (int j = 0; j < 8; j++) {
        int k = kbase + j;
        float f = 0.f;
        if (col < C) {
            if (k < KSH * 32) {
                if (k < K1) f = W1[(size_t)k * C + col];
            } else {
                int k2 = k - KSH * 32;
                if (k2 < K2) f = W2[(size_t)k2 * C + col];
            }
        }
        v[j] = (unsigned short)bf16_rn(f);
    }
    uint4 o;
    o.x = v[0] | ((unsigned)v[1] << 16);
    o.y = v[2] | ((unsigned)v[3] << 16);
    o.z = v[4] | ((unsigned)v[5] << 16);
    o.w = v[6] | ((unsigned)v[7] << 16);
    Wp[idx] = o;
}

// ---------------- MFMA GEMM: out = post([A|B] @ Wp + bias) -----------------
template <int KS, int KSH, int CT, int C, int OST, int NORM, int ACT, int OUTF>
__global__ __launch_bounds__(256) void k_gemm(
    const uint4* __restrict__ A, const uint4* __restrict__ Bb,
    const uint4* __restrict__ Wp, const float* __restrict__ bias,
    void* __restrict__ outv, int n) {
    int l = threadIdx.x & 63;
    int wv = threadIdx.x >> 6;
    int rb = blockIdx.x * 64 + wv * 16;
    int rowA = rb + (l & 15);
    if (rowA >= n) rowA = n - 1;           // clamp; stores are guarded
    int koct = l >> 4;
    const int strideU = KSH * 4;           // uint4 per row
    size_t baseA = (size_t)rowA * strideU + koct;

    f32x4 acc[CT];
#pragma unroll
    for (int ct = 0; ct < CT; ct++) acc[ct] = (f32x4){0.f, 0.f, 0.f, 0.f};

#pragma unroll
    for (int ks = 0; ks < KS; ks++) {
        U4B8 a;
        a.u = (ks < KSH) ? A[baseA + ks * 4] : Bb[baseA + (ks - KSH) * 4];
#pragma unroll
        for (int ct = 0; ct < CT; ct++) {
            U4B8 b;
            b.u = Wp[(ct * KS + ks) * 64 + l];
            acc[ct] = __builtin_amdgcn_mfma_f32_16x16x32_bf16(a.b, b.b, acc[ct], 0, 0, 0);
        }
    }

    int cid = l & 15;
    int grp = l >> 4;
#pragma unroll
    for (int ct = 0; ct < CT; ct++) {
        int col = ct * 16 + cid;
        float bv = (col < C) ? bias[col] : 0.f;
#pragma unroll
        for (int r = 0; r < 4; r++) acc[ct][r] += bv;
    }

    if (NORM) {
        float ss[4];
#pragma unroll
        for (int r = 0; r < 4; r++) {
            ss[r] = 0.f;
#pragma unroll
            for (int ct = 0; ct < CT; ct++) ss[r] += acc[ct][r] * acc[ct][r];
        }
#pragma unroll
        for (int off = 1; off < 16; off <<= 1) {
#pragma unroll
            for (int r = 0; r < 4; r++) ss[r] += __shfl_xor(ss[r], off, 64);
        }
#pragma unroll
        for (int r = 0; r < 4; r++) {
            float sc = 1.0f / fmaxf(sqrtf(ss[r]), 1e-12f);
#pragma unroll
            for (int ct = 0; ct < CT; ct++) acc[ct][r] *= sc;
        }
    }

    if (ACT) {
#pragma unroll
        for (int ct = 0; ct < CT; ct++)
#pragma unroll
            for (int r = 0; r < 4; r++) acc[ct][r] = LRELU(acc[ct][r]);
    }

#pragma unroll
    for (int r = 0; r < 4; r++) {
        int row = rb + grp * 4 + r;
        if (row >= n) continue;
        if (OUTF) {
            float* o = (float*)outv;
#pragma unroll
            for (int ct = 0; ct < CT; ct++) {
                int col = ct * 16 + cid;
                if (col < OST) o[(size_t)row * OST + col] = acc[ct][r];
            }
        } else {
            unsigned short* o = (unsigned short*)outv;
#pragma unroll
            for (int ct = 0; ct < CT; ct++) {
                int col = ct * 16 + cid;
                if (col < OST) o[(size_t)row * OST + col] = (unsigned short)bf16_rn(acc[ct][r]);
            }
        }
    }
}

// ---------------- global add-pool: wave per 64 rows, coalesced -------------
__global__ __launch_bounds__(256) void k_pool(const float* __restrict__ x,
                                              const int* __restrict__ batch,
                                              float* __restrict__ g, int n) {
    __shared__ float sm[8][64];
    __shared__ int sb[8];
    int lane = threadIdx.x & 63;
    int wv = threadIdx.x >> 6;
    int base = blockIdx.x * 256 + wv * 64;
    float a0 = 0.f, a1 = 0.f;
    int b0 = -1, b1 = -1;
    int end = (base + 64 < n) ? base + 64 : n;
    for (int row = base; row < end; row++) {
        int bg = batch[row];
        float v = x[(size_t)row * 64 + lane];
        if (b0 < 0) b0 = bg;
        if (bg == b0) a0 += v;
        else { if (b1 < 0) b1 = bg; a1 += v; }
    }
    sm[wv * 2 + 0][lane] = a0;
    sm[wv * 2 + 1][lane] = a1;
    if (lane == 0) {
        sb[wv * 2 + 0] = b0;
        sb[wv * 2 + 1] = b1;
    }
    __syncthreads();
    if (wv == 0) {
        float c0 = 0.f, c1 = 0.f;
        int d0 = -1, d1 = -1;
#pragma unroll
        for (int s = 0; s < 8; s++) {
            int bg = sb[s];
            if (bg < 0) continue;
            float v = sm[s][lane];
            if (d0 < 0) d0 = bg;
            if (bg == d0) c0 += v;
            else { if (d1 < 0) d1 = bg; c1 += v; }
        }
        if (d0 >= 0) atomicAdd(&g[d0 * 64 + lane], c0);
        if (d1 >= 0) atomicAdd(&g[d1 * 64 + lane], c1);
    }
}

// ---------------- post MLP ----------------
__global__ void k_post1(const float* __restrict__ g, const float* __restrict__ cf,
                        const int* __restrict__ ncfg, const float* __restrict__ w1,
                        const float* __restrict__ b1, float* __restrict__ z,
                        int BC, int B) {
    int idx = blockIdx.x * 256 + threadIdx.x;
    if (idx >= BC * 64) return;
    int row = idx >> 6, c = idx & 63;
    int gsum = 0, gid = B - 1;
    for (int b2 = 0; b2 < B; b2++) {
        int ns = ncfg[b2];
        if (row < gsum + ns) { gid = b2; break; }
        gsum += ns;
    }
    float acc = b1[c];
#pragma unroll 4
    for (int k = 0; k < 64; k++) acc += g[gid * 64 + k] * w1[k * 64 + c];
#pragma unroll 4
    for (int k = 0; k < 24; k++) acc += cf[(size_t)row * 24 + k] * w1[(64 + k) * 64 + c];
    z[idx] = LRELU(acc);
}

__global__ void k_post2(const float* __restrict__ z, const float* __restrict__ w2,
                        const float* __restrict__ b2, float* __restrict__ out, int BC) {
    int row = blockIdx.x * 4 + (threadIdx.x >> 6);
    if (row >= BC) return;
    int c = threadIdx.x & 63;
    float v = z[(size_t)row * 64 + c] * w2[c];
#pragma unroll
    for (int off = 32; off > 0; off >>= 1) v += __shfl_xor(v, off, 64);
    if (c == 0) out[row] = v + b2[0];
}

// ---------------------------------------------------------------------------
extern "C" void kernel_launch(void* const* d_in, const int* in_sizes, int n_in,
                              void* d_out, int out_size, void* d_ws, size_t ws_size,
                              hipStream_t stream) {
    const float* node_feat = (const float*)d_in[0];
    const int*   opcode    = (const int*)d_in[1];
    const int*   ei        = (const int*)d_in[2];
    const float* cf        = (const float*)d_in[3];
    const int*   ncfg      = (const int*)d_in[4];
    const int*   batch     = (const int*)d_in[5];
    const float* emb       = (const float*)d_in[6];
    const float* wl0 = (const float*)d_in[7];
    const float* bl0 = (const float*)d_in[8];
    const float* wr0 = (const float*)d_in[9];
    const float* lw0 = (const float*)d_in[10];
    const float* lb0 = (const float*)d_in[11];
    const float* wl1 = (const float*)d_in[12];
    const float* bl1 = (const float*)d_in[13];
    const float* wr1 = (const float*)d_in[14];
    const float* lw1 = (const float*)d_in[15];
    const float* lb1 = (const float*)d_in[16];
    const float* wl2 = (const float*)d_in[17];
    const float* bl2 = (const float*)d_in[18];
    const float* wr2 = (const float*)d_in[19];
    const float* lw2 = (const float*)d_in[20];
    const float* lb2 = (const float*)d_in[21];
    const float* pw1 = (const float*)d_in[22];
    const float* pb1 = (const float*)d_in[23];
    const float* pw2 = (const float*)d_in[24];
    const float* pb2 = (const float*)d_in[25];

    const int N  = in_sizes[0] / 140;
    const int E  = in_sizes[2] / 2;
    const int B  = in_sizes[4];
    const int BC = in_sizes[3] / 24;
    const int NBUCK = (N + 127) >> 7;

    char* w = (char*)d_ws;
    auto alloc = [&](size_t bytes) {
        void* p = (void*)w;
        w += (bytes + 255) & ~(size_t)255;
        return p;
    };
    int*      bcnt     = (int*)alloc(1024 * 4);
    int*      bo       = (int*)alloc(1025 * 4);
    int*      bfill    = (int*)alloc(1024 * 4);
    uint2*    pairs    = (uint2*)alloc((size_t)2 * E * 8);
    int*      rp       = (int*)alloc((size_t)(N + 1) * 4);
    float*    invd     = (float*)alloc((size_t)N * 4);
    int*      csr      = (int*)alloc((size_t)2 * E * 4);
    unsigned* X0       = (unsigned*)alloc((size_t)N * 80 * 4);   // bf16, stride 160
    unsigned* AG0      = (unsigned*)alloc((size_t)N * 80 * 4);
    unsigned* H0       = (unsigned*)alloc((size_t)N * 80 * 4);
    unsigned* T0       = (unsigned*)alloc((size_t)N * 32 * 4);   // bf16, stride 64
    unsigned* T1       = (unsigned*)alloc((size_t)N * 32 * 4);
    unsigned* T2       = (unsigned*)alloc((size_t)N * 32 * 4);
    float*    X3F      = (float*)alloc((size_t)N * 64 * 4);      // final x, f32
    float*    gbuf     = (float*)alloc((size_t)B * 64 * 4);
    float*    zp       = (float*)alloc((size_t)BC * 64 * 4);
    uint4*    Wp0h     = (uint4*)alloc((size_t)10 * 10 * 64 * 16);
    uint4*    Wp0l     = (uint4*)alloc((size_t)4 * 10 * 64 * 16);
    uint4*    Wp1h     = (uint4*)alloc((size_t)4 * 4 * 64 * 16);
    uint4*    Wp1l     = (uint4*)alloc((size_t)4 * 4 * 64 * 16);
    uint4*    Wp2h     = (uint4*)alloc((size_t)4 * 4 * 64 * 16);
    uint4*    Wp2l     = (uint4*)alloc((size_t)4 * 4 * 64 * 16);
    (void)ws_size; (void)n_in; (void)out_size;

    hipMemsetAsync(bcnt, 0, 1024 * 4, stream);
    hipMemsetAsync(gbuf, 0, (size_t)B * 64 * 4, stream);

    // weight pre-pack (tiny)
    k_prep<10, 5, 10, 148><<<(6400 + 255) / 256, 256, 0, stream>>>(wl0, wr0, 148, 148, Wp0h);
    k_prep<10, 5, 4, 64><<<(2560 + 255) / 256, 256, 0, stream>>>(lw0, lw0 + 148 * 64, 148, 148, Wp0l);
    k_prep<4, 2, 4, 64><<<4, 256, 0, stream>>>(wl1, wr1, 64, 64, Wp1h);
    k_prep<4, 2, 4, 64><<<4, 256, 0, stream>>>(lw1, lw1 + 64 * 64, 64, 64, Wp1l);
    k_prep<4, 2, 4, 64><<<4, 256, 0, stream>>>(wl2, wr2, 64, 64, Wp2h);
    k_prep<4, 2, 4, 64><<<4, 256, 0, stream>>>(lw2, lw2 + 64 * 64, 64, 64, Wp2l);

    k_concat<<<(N * 80 + 255) / 256, 256, 0, stream>>>(node_feat, opcode, emb, X0, N);

    // bucketed CSR build
    const int EB = (E + 4095) / 4096;
    k_bh<<<EB, 256, 0, stream>>>(ei, E, NBUCK, bcnt);
    k_bscan<<<1, 1024, 0, stream>>>(bcnt, NBUCK, bo, bfill);
    k_bscatter<<<EB, 256, 0, stream>>>(ei, E, bfill, pairs);
    k_bfinal<<<NBUCK, 256, 0, stream>>>(pairs, bo, rp, csr, invd, N, NBUCK);

    const int AGG_GRID  = (N + 3) / 4;
    const int GEMM_GRID = (N + 63) / 64;

    // ---- layer 0 ----
    k_agg160<<<AGG_GRID, 256, 0, stream>>>(X0, rp, csr, invd, AG0, N);
    k_gemm<10, 5, 10, 148, 160, 1, 0, 0><<<GEMM_GRID, 256, 0, stream>>>(
        (const uint4*)AG0, (const uint4*)X0, Wp0h, bl0, H0, N);
    k_gemm<10, 5, 4, 64, 64, 0, 1, 0><<<GEMM_GRID, 256, 0, stream>>>(
        (const uint4*)H0, (const uint4*)X0, Wp0l, lb0, T0, N);

    // ---- layer 1 ----
    k_agg64<<<AGG_GRID, 256, 0, stream>>>(T0, rp, csr, invd, T1, N);
    k_gemm<4, 2, 4, 64, 64, 1, 0, 0><<<GEMM_GRID, 256, 0, stream>>>(
        (const uint4*)T1, (const uint4*)T0, Wp1h, bl1, T2, N);
    k_gemm<4, 2, 4, 64, 64, 0, 1, 0><<<GEMM_GRID, 256, 0, stream>>>(
        (const uint4*)T2, (const uint4*)T0, Wp1l, lb1, T1, N);

    // ---- layer 2 ----
    k_agg64<<<AGG_GRID, 256, 0, stream>>>(T1, rp, csr, invd, T0, N);
    k_gemm<4, 2, 4, 64, 64, 1, 0, 0><<<GEMM_GRID, 256, 0, stream>>>(
        (const uint4*)T0, (const uint4*)T1, Wp2h, bl2, T2, N);
    k_gemm<4, 2, 4, 64, 64, 0, 1, 1><<<GEMM_GRID, 256, 0, stream>>>(
        (const uint4*)T2, (const uint4*)T1, Wp2l, lb2, X3F, N);

    // pool + post MLP
    k_pool<<<(N + 255) / 256, 256, 0, stream>>>(X3F, batch, gbuf, N);
    k_post1<<<(BC * 64 + 255) / 256, 256, 0, stream>>>(gbuf, cf, ncfg, pw1, pb1, zp, BC, B);
    k_post2<<<(BC + 3) / 4, 256, 0, stream>>>(zp, pw2, pb2, (float*)d_out, BC);
}

// Round 7
// 545.684 us; speedup vs baseline: 3.1751x; 1.0759x over previous
//
#include <hip/hip_runtime.h>
#include <cstdint>
#include <cstddef>

// ---------------------------------------------------------------------------
// LateJoinSAGE round 7: round 6 with compile fix — cvt_pk_f32_fp8's hi-half
// selector must be a literal constant, so fp8x2_dec is now template<bool HI>.
// fp8-e4m3 gather copy for layer-0 aggregation (halves dominant gather
// traffic); X0 stays bf16 for GEMMs; X08 aliases the dead pairs buffer.
// ---------------------------------------------------------------------------

#define LRELU(v) ((v) > 0.f ? (v) : 0.01f * (v))

typedef __attribute__((ext_vector_type(8))) short bf16x8;
typedef __attribute__((ext_vector_type(4))) float f32x4;
typedef float floatx2 __attribute__((ext_vector_type(2)));

union U4B8 {
    uint4 u;
    bf16x8 b;
};

__device__ inline unsigned bf16_rn(float x) {
    unsigned u = __float_as_uint(x);
    return (u + 0x7fffu + ((u >> 16) & 1u)) >> 16;
}
__device__ inline unsigned pack2(float lo, float hi) {
    return bf16_rn(lo) | (bf16_rn(hi) << 16);
}
__device__ inline float2 up2(unsigned v) {
    return make_float2(__uint_as_float(v << 16), __uint_as_float(v & 0xffff0000u));
}

// ---------------- fp8 e4m3 helpers ----------------
__device__ inline float e4m3_to_f32(unsigned b) {
    float v = __uint_as_float((b & 0x7fu) << 20) * 0x1p120f;
    return __uint_as_float(__float_as_uint(v) | ((b & 0x80u) << 24));
}

template <bool HI>
__device__ inline floatx2 fp8x2_dec(unsigned v) {
#if __has_builtin(__builtin_amdgcn_cvt_pk_f32_fp8)
    return __builtin_amdgcn_cvt_pk_f32_fp8((int)v, HI);
#else
    unsigned w = HI ? (v >> 16) : v;
    floatx2 r;
    r.x = e4m3_to_f32(w & 0xffu);
    r.y = e4m3_to_f32((w >> 8) & 0xffu);
    return r;
#endif
}

__device__ inline unsigned char f32_to_e4m3_sw(float f) {
    unsigned u = __float_as_uint(f);
    unsigned s = (u >> 24) & 0x80u;
    float a = fabsf(f);
    if (a > 448.f) a = 448.f;
    unsigned b = __float_as_uint(a);
    int exp = (int)(b >> 23) - 127;
    unsigned r;
    if (exp < -9) {
        r = 0;
    } else if (exp >= -6) {
        unsigned m = b & 0x7fffffu;
        unsigned keep = m >> 20;
        unsigned rb = (m >> 19) & 1u;
        unsigned sticky = (m & 0x7ffffu) ? 1u : 0u;
        unsigned inc = rb & (sticky | (keep & 1u));
        unsigned em = (((unsigned)(exp + 7)) << 3) | keep;
        em += inc;
        if (em > 0x7eu) em = 0x7eu;
        r = em;
    } else {
        float t = a * 512.f;
        int q = (int)(t + 0.5f);
        r = (q > 7) ? 0x08u : (unsigned)q;
    }
    return (unsigned char)(r | s);
}

__device__ inline unsigned fp8x4_enc(float f0, float f1, float f2, float f3) {
#if __has_builtin(__builtin_amdgcn_cvt_pk_fp8_f32)
    int pk = __builtin_amdgcn_cvt_pk_fp8_f32(f0, f1, 0, false);
    pk = __builtin_amdgcn_cvt_pk_fp8_f32(f2, f3, pk, true);
    return (unsigned)pk;
#else
    return (unsigned)f32_to_e4m3_sw(f0) | ((unsigned)f32_to_e4m3_sw(f1) << 8) |
           ((unsigned)f32_to_e4m3_sw(f2) << 16) | ((unsigned)f32_to_e4m3_sw(f3) << 24);
#endif
}

// ---------------- x0 concat -> bf16 (stride 160) + fp8 (stride 160B) -------
__global__ void k_concat(const float* __restrict__ nf, const int* __restrict__ opc,
                         const float* __restrict__ emb, unsigned* __restrict__ x0,
                         unsigned* __restrict__ x8, int n) {
    int idx = blockIdx.x * 256 + threadIdx.x;
    if (idx >= n * 40) return;
    int node = idx / 40;
    int u = idx - node * 40;
    float f[4];
#pragma unroll
    for (int j = 0; j < 4; j++) {
        int ft = 4 * u + j;
        float v = 0.f;
        if (ft < 140) v = nf[(size_t)node * 140 + ft];
        else if (ft < 148) v = emb[opc[node] * 8 + (ft - 140)];
        f[j] = v;
    }
    ((uint2*)x0)[idx] = make_uint2(pack2(f[0], f[1]), pack2(f[2], f[3]));
    x8[idx] = fp8x4_enc(f[0], f[1], f[2], f[3]);
}

// ---------------- bucketed CSR build ----------------
__global__ __launch_bounds__(256) void k_bh(const int* __restrict__ ei, int E,
                                            int NBUCK, int* __restrict__ bcnt) {
    __shared__ int h[1024];
    int t = threadIdx.x;
    for (int i = t; i < 1024; i += 256) h[i] = 0;
    __syncthreads();
    int e0 = blockIdx.x * 4096, e1 = min(E, e0 + 4096);
    for (int e = e0 + t; e < e1; e += 256) {
        int a = ei[2 * e], b = ei[2 * e + 1];
        atomicAdd(&h[b >> 7], 1);
        atomicAdd(&h[a >> 7], 1);
    }
    __syncthreads();
    for (int i = t; i < NBUCK; i += 256)
        if (h[i]) atomicAdd(&bcnt[i], h[i]);
}

__global__ void k_bscan(const int* __restrict__ bcnt, int NBUCK,
                        int* __restrict__ bo, int* __restrict__ bfill) {
    __shared__ int sm[1024];
    int t = threadIdx.x;
    int v = (t < NBUCK) ? bcnt[t] : 0;
    sm[t] = v;
    __syncthreads();
    for (int off = 1; off < 1024; off <<= 1) {
        int u = 0;
        if (t >= off) u = sm[t - off];
        __syncthreads();
        sm[t] += u;
        __syncthreads();
    }
    if (t < NBUCK) {
        int ex = sm[t] - v;
        bo[t] = ex;
        bfill[t] = ex;
    }
    if (t == NBUCK - 1) bo[NBUCK] = sm[t];
}

__global__ __launch_bounds__(256) void k_bscatter(const int* __restrict__ ei, int E,
                                                  int* __restrict__ bfill,
                                                  uint2* __restrict__ pairs) {
    __shared__ int hist[1024], lbo[1024], gb[1024], cur[1024];
    __shared__ int wsum[4];
    __shared__ int stageD[8192];
    __shared__ int stageS[8192];
    int t = threadIdx.x;
    for (int i = t; i < 1024; i += 256) hist[i] = 0;
    __syncthreads();
    int e0 = blockIdx.x * 4096, e1 = min(E, e0 + 4096);
    for (int e = e0 + t; e < e1; e += 256) {
        int a = ei[2 * e], b = ei[2 * e + 1];
        atomicAdd(&hist[b >> 7], 1);
        atomicAdd(&hist[a >> 7], 1);
    }
    __syncthreads();
    int b4 = t * 4;
    int c0 = hist[b4], c1 = hist[b4 + 1], c2 = hist[b4 + 2], c3 = hist[b4 + 3];
    int ms = c0 + c1 + c2 + c3;
    int lane = t & 63, wv = t >> 6;
    int v = ms;
#pragma unroll
    for (int off = 1; off < 64; off <<= 1) {
        int u = __shfl_up(v, off, 64);
        if (lane >= off) v += u;
    }
    if (lane == 63) wsum[wv] = v;
    __syncthreads();
    int wb = 0;
    for (int i = 0; i < wv; i++) wb += wsum[i];
    int ex = wb + v - ms;
    lbo[b4] = ex;
    lbo[b4 + 1] = ex + c0;
    lbo[b4 + 2] = ex + c0 + c1;
    lbo[b4 + 3] = ex + c0 + c1 + c2;
    if (c0) gb[b4 + 0] = atomicAdd(&bfill[b4 + 0], c0);
    if (c1) gb[b4 + 1] = atomicAdd(&bfill[b4 + 1], c1);
    if (c2) gb[b4 + 2] = atomicAdd(&bfill[b4 + 2], c2);
    if (c3) gb[b4 + 3] = atomicAdd(&bfill[b4 + 3], c3);
    cur[b4] = 0;
    cur[b4 + 1] = 0;
    cur[b4 + 2] = 0;
    cur[b4 + 3] = 0;
    __syncthreads();
    for (int e = e0 + t; e < e1; e += 256) {
        int a = ei[2 * e], b = ei[2 * e + 1];
        int bk = b >> 7;
        int r = atomicAdd(&cur[bk], 1);
        int p = lbo[bk] + r;
        stageD[p] = b;
        stageS[p] = a;
        bk = a >> 7;
        r = atomicAdd(&cur[bk], 1);
        p = lbo[bk] + r;
        stageD[p] = a;
        stageS[p] = b;
    }
    __syncthreads();
    int tot = 2 * (e1 - e0);
    for (int i = t; i < tot; i += 256) {
        int d = stageD[i];
        int bk = d >> 7;
        pairs[gb[bk] + (i - lbo[bk])] = make_uint2((unsigned)d, (unsigned)stageS[i]);
    }
}

__global__ __launch_bounds__(256) void k_bfinal(const uint2* __restrict__ pairs,
                                                const int* __restrict__ bo,
                                                int* __restrict__ rp,
                                                int* __restrict__ csr,
                                                float* __restrict__ invd,
                                                int N, int NBUCK) {
    __shared__ int hist[128], ls[128], cur[128];
    __shared__ unsigned outS[6144];
    int t = threadIdx.x;
    int bk = blockIdx.x;
    int n0 = bk << 7;
    int nn = min(128, N - n0);
    int base = bo[bk], cnt = bo[bk + 1] - base;
    if (t < 128) {
        hist[t] = 0;
        cur[t] = 0;
    }
    __syncthreads();
    for (int i = t; i < cnt; i += 256) atomicAdd(&hist[(int)pairs[base + i].x - n0], 1);
    __syncthreads();
    if (t == 0) {
        int run = 0;
        for (int i = 0; i < 128; i++) {
            ls[i] = run;
            run += hist[i];
        }
    }
    __syncthreads();
    if (t < nn) {
        int node = n0 + t;
        rp[node] = base + ls[t];
        invd[node] = 1.0f / fmaxf((float)hist[t], 1.0f);
    }
    if (bk == NBUCK - 1 && t == 0) rp[N] = base + cnt;
    bool inl = (cnt <= 6144);
    for (int i = t; i < cnt; i += 256) {
        uint2 pr = pairs[base + i];
        int loc = (int)pr.x - n0;
        int r = atomicAdd(&cur[loc], 1);
        int pos = ls[loc] + r;
        if (inl) outS[pos] = pr.y;
        else csr[base + pos] = (int)pr.y;
    }
    __syncthreads();
    if (inl)
        for (int i = t; i < cnt; i += 256) csr[base + i] = (int)outS[i];
}

// ---------------- layer-0 aggregation from fp8 rows (40 uints/row) ---------
__global__ __launch_bounds__(256) void k_agg160(
    const unsigned* __restrict__ x8, const int* __restrict__ rp,
    const int* __restrict__ csr, const float* __restrict__ invd,
    unsigned* __restrict__ agg, int n) {
    int wave = threadIdx.x >> 6;
    int l = threadIdx.x & 63;
    int node = blockIdx.x * 4 + wave;
    if (node >= n) return;
    int p = l & 31;        // main uint idx (features 4p..4p+3)
    int h = l >> 5;        // neighbor half
    int eg = l >> 3;       // ext neighbor slot 0..7
    int eq = l & 7;        // ext uint (features 128+4eq..)
    float am[4] = {0.f, 0.f, 0.f, 0.f};
    float ae[4] = {0.f, 0.f, 0.f, 0.f};
    int s = rp[node], e2 = rp[node + 1];
    int j = s;
    for (; j + 8 <= e2; j += 8) {
#pragma unroll
        for (int i = 0; i < 4; i++) {
            int u = csr[j + 2 * i + h];
            unsigned v = x8[(size_t)u * 40 + p];
            floatx2 lo = fp8x2_dec<false>(v);
            floatx2 hi = fp8x2_dec<true>(v);
            am[0] += lo.x;
            am[1] += lo.y;
            am[2] += hi.x;
            am[3] += hi.y;
        }
        int ue = csr[j + eg];
        unsigned v = x8[(size_t)ue * 40 + 32 + eq];
        floatx2 lo = fp8x2_dec<false>(v);
        floatx2 hi = fp8x2_dec<true>(v);
        ae[0] += lo.x;
        ae[1] += lo.y;
        ae[2] += hi.x;
        ae[3] += hi.y;
    }
    for (; j < e2; j++) {
        int u = csr[j];
        if (l < 32) {
            unsigned v = x8[(size_t)u * 40 + p];
            floatx2 lo = fp8x2_dec<false>(v);
            floatx2 hi = fp8x2_dec<true>(v);
            am[0] += lo.x;
            am[1] += lo.y;
            am[2] += hi.x;
            am[3] += hi.y;
        } else if (l < 40) {
            unsigned v = x8[(size_t)u * 40 + 32 + eq];
            floatx2 lo = fp8x2_dec<false>(v);
            floatx2 hi = fp8x2_dec<true>(v);
            ae[0] += lo.x;
            ae[1] += lo.y;
            ae[2] += hi.x;
            ae[3] += hi.y;
        }
    }
#pragma unroll
    for (int r = 0; r < 4; r++) am[r] += __shfl_xor(am[r], 32, 64);
#pragma unroll
    for (int r = 0; r < 4; r++) {
        ae[r] += __shfl_xor(ae[r], 8, 64);
        ae[r] += __shfl_xor(ae[r], 16, 64);
        ae[r] += __shfl_xor(ae[r], 32, 64);
    }
    float iv = invd[node];
    unsigned* row = agg + (size_t)node * 80;
    if (l < 32)
        ((uint2*)row)[p] = make_uint2(pack2(am[0] * iv, am[1] * iv),
                                      pack2(am[2] * iv, am[3] * iv));
    if (l < 8)
        ((uint2*)(row + 64))[eq] = make_uint2(pack2(ae[0] * iv, ae[1] * iv),
                                              pack2(ae[2] * iv, ae[3] * iv));
}

// ---------------- 64-dim aggregation (bf16) ----------------
__global__ __launch_bounds__(256) void k_agg64(
    const unsigned* __restrict__ x, const int* __restrict__ rp,
    const int* __restrict__ csr, const float* __restrict__ invd,
    unsigned* __restrict__ agg, int n) {
    int wave = threadIdx.x >> 6;
    int lane = threadIdx.x & 63;
    int node = blockIdx.x * 4 + wave;
    if (node >= n) return;
    int p = lane & 31;
    int h = lane >> 5;
    float a0 = 0.f, a1 = 0.f;
    int s = rp[node], e2 = rp[node + 1];
    int j = s;
    for (; j + 8 <= e2; j += 8) {
        int u0 = csr[j + 0 + h];
        int u1 = csr[j + 2 + h];
        int u2 = csr[j + 4 + h];
        int u3 = csr[j + 6 + h];
        float2 v0 = up2(x[(size_t)u0 * 32 + p]);
        float2 v1 = up2(x[(size_t)u1 * 32 + p]);
        float2 v2 = up2(x[(size_t)u2 * 32 + p]);
        float2 v3 = up2(x[(size_t)u3 * 32 + p]);
        a0 += (v0.x + v1.x) + (v2.x + v3.x);
        a1 += (v0.y + v1.y) + (v2.y + v3.y);
    }
    for (; j < e2; j += 2) {
        int idx = j + h;
        if (idx < e2) {
            int u = csr[idx];
            float2 v = up2(x[(size_t)u * 32 + p]);
            a0 += v.x;
            a1 += v.y;
        }
    }
    a0 += __shfl_xor(a0, 32, 64);
    a1 += __shfl_xor(a1, 32, 64);
    if (lane < 32) {
        float iv = invd[node];
        agg[(size_t)node * 32 + p] = pack2(a0 * iv, a1 * iv);
    }
}

// ---------------- weight pre-pack into B-fragment order --------------------
template <int KS, int KSH, int CT, int C>
__global__ void k_prep(const float* __restrict__ W1, const float* __restrict__ W2,
                       int K1, int K2, uint4* __restrict__ Wp) {
    int idx = blockIdx.x * 256 + threadIdx.x;
    if (idx >= CT * KS * 64) return;
    int l = idx & 63;
    int ks = (idx >> 6) % KS;
    int ct = idx / (KS * 64);
    int col = ct * 16 + (l & 15);
    int kbase = ks * 32 + (l >> 4) * 8;
    unsigned short v[8];
#pragma unroll
    for (int j = 0; j < 8; j++) {
        int k = kbase + j;
        float f = 0.f;
        if (col < C) {
            if (k < KSH * 32) {
                if (k < K1) f = W1[(size_t)k * C + col];
            } else {
                int k2 = k - KSH * 32;
                if (k2 < K2) f = W2[(size_t)k2 * C + col];
            }
        }
        v[j] = (unsigned short)bf16_rn(f);
    }
    uint4 o;
    o.x = v[0] | ((unsigned)v[1] << 16);
    o.y = v[2] | ((unsigned)v[3] << 16);
    o.z = v[4] | ((unsigned)v[5] << 16);
    o.w = v[6] | ((unsigned)v[7] << 16);
    Wp[idx] = o;
}

// ---------------- MFMA GEMM: out = post([A|B] @ Wp + bias) -----------------
template <int KS, int KSH, int CT, int C, int OST, int NORM, int ACT, int OUTF>
__global__ __launch_bounds__(256) void k_gemm(
    const uint4* __restrict__ A, const uint4* __restrict__ Bb,
    const uint4* __restrict__ Wp, const float* __restrict__ bias,
    void* __restrict__ outv, int n) {
    int l = threadIdx.x & 63;
    int wv = threadIdx.x >> 6;
    int rb = blockIdx.x * 64 + wv * 16;
    int rowA = rb + (l & 15);
    if (rowA >= n) rowA = n - 1;           // clamp; stores are guarded
    int koct = l >> 4;
    const int strideU = KSH * 4;           // uint4 per row
    size_t baseA = (size_t)rowA * strideU + koct;

    f32x4 acc[CT];
#pragma unroll
    for (int ct = 0; ct < CT; ct++) acc[ct] = (f32x4){0.f, 0.f, 0.f, 0.f};

#pragma unroll
    for (int ks = 0; ks < KS; ks++) {
        U4B8 a;
        a.u = (ks < KSH) ? A[baseA + ks * 4] : Bb[baseA + (ks - KSH) * 4];
#pragma unroll
        for (int ct = 0; ct < CT; ct++) {
            U4B8 b;
            b.u = Wp[(ct * KS + ks) * 64 + l];
            acc[ct] = __builtin_amdgcn_mfma_f32_16x16x32_bf16(a.b, b.b, acc[ct], 0, 0, 0);
        }
    }

    int cid = l & 15;
    int grp = l >> 4;
#pragma unroll
    for (int ct = 0; ct < CT; ct++) {
        int col = ct * 16 + cid;
        float bv = (col < C) ? bias[col] : 0.f;
#pragma unroll
        for (int r = 0; r < 4; r++) acc[ct][r] += bv;
    }

    if (NORM) {
        float ss[4];
#pragma unroll
        for (int r = 0; r < 4; r++) {
            ss[r] = 0.f;
#pragma unroll
            for (int ct = 0; ct < CT; ct++) ss[r] += acc[ct][r] * acc[ct][r];
        }
#pragma unroll
        for (int off = 1; off < 16; off <<= 1) {
#pragma unroll
            for (int r = 0; r < 4; r++) ss[r] += __shfl_xor(ss[r], off, 64);
        }
#pragma unroll
        for (int r = 0; r < 4; r++) {
            float sc = 1.0f / fmaxf(sqrtf(ss[r]), 1e-12f);
#pragma unroll
            for (int ct = 0; ct < CT; ct++) acc[ct][r] *= sc;
        }
    }

    if (ACT) {
#pragma unroll
        for (int ct = 0; ct < CT; ct++)
#pragma unroll
            for (int r = 0; r < 4; r++) acc[ct][r] = LRELU(acc[ct][r]);
    }

#pragma unroll
    for (int r = 0; r < 4; r++) {
        int row = rb + grp * 4 + r;
        if (row >= n) continue;
        if (OUTF) {
            float* o = (float*)outv;
#pragma unroll
            for (int ct = 0; ct < CT; ct++) {
                int col = ct * 16 + cid;
                if (col < OST) o[(size_t)row * OST + col] = acc[ct][r];
            }
        } else {
            unsigned short* o = (unsigned short*)outv;
#pragma unroll
            for (int ct = 0; ct < CT; ct++) {
                int col = ct * 16 + cid;
                if (col < OST) o[(size_t)row * OST + col] = (unsigned short)bf16_rn(acc[ct][r]);
            }
        }
    }
}

// ---------------- global add-pool: wave per 64 rows, coalesced -------------
__global__ __launch_bounds__(256) void k_pool(const float* __restrict__ x,
                                              const int* __restrict__ batch,
                                              float* __restrict__ g, int n) {
    __shared__ float sm[8][64];
    __shared__ int sb[8];
    int lane = threadIdx.x & 63;
    int wv = threadIdx.x >> 6;
    int base = blockIdx.x * 256 + wv * 64;
    float a0 = 0.f, a1 = 0.f;
    int b0 = -1, b1 = -1;
    int end = (base + 64 < n) ? base + 64 : n;
    for (int row = base; row < end; row++) {
        int bg = batch[row];
        float v = x[(size_t)row * 64 + lane];
        if (b0 < 0) b0 = bg;
        if (bg == b0) a0 += v;
        else { if (b1 < 0) b1 = bg; a1 += v; }
    }
    sm[wv * 2 + 0][lane] = a0;
    sm[wv * 2 + 1][lane] = a1;
    if (lane == 0) {
        sb[wv * 2 + 0] = b0;
        sb[wv * 2 + 1] = b1;
    }
    __syncthreads();
    if (wv == 0) {
        float c0 = 0.f, c1 = 0.f;
        int d0 = -1, d1 = -1;
#pragma unroll
        for (int s = 0; s < 8; s++) {
            int bg = sb[s];
            if (bg < 0) continue;
            float v = sm[s][lane];
            if (d0 < 0) d0 = bg;
            if (bg == d0) c0 += v;
            else { if (d1 < 0) d1 = bg; c1 += v; }
        }
        if (d0 >= 0) atomicAdd(&g[d0 * 64 + lane], c0);
        if (d1 >= 0) atomicAdd(&g[d1 * 64 + lane], c1);
    }
}

// ---------------- post MLP ----------------
__global__ void k_post1(const float* __restrict__ g, const float* __restrict__ cf,
                        const int* __restrict__ ncfg, const float* __restrict__ w1,
                        const float* __restrict__ b1, float* __restrict__ z,
                        int BC, int B) {
    int idx = blockIdx.x * 256 + threadIdx.x;
    if (idx >= BC * 64) return;
    int row = idx >> 6, c = idx & 63;
    int gsum = 0, gid = B - 1;
    for (int b2 = 0; b2 < B; b2++) {
        int ns = ncfg[b2];
        if (row < gsum + ns) { gid = b2; break; }
        gsum += ns;
    }
    float acc = b1[c];
#pragma unroll 4
    for (int k = 0; k < 64; k++) acc += g[gid * 64 + k] * w1[k * 64 + c];
#pragma unroll 4
    for (int k = 0; k < 24; k++) acc += cf[(size_t)row * 24 + k] * w1[(64 + k) * 64 + c];
    z[idx] = LRELU(acc);
}

__global__ void k_post2(const float* __restrict__ z, const float* __restrict__ w2,
                        const float* __restrict__ b2, float* __restrict__ out, int BC) {
    int row = blockIdx.x * 4 + (threadIdx.x >> 6);
    if (row >= BC) return;
    int c = threadIdx.x & 63;
    float v = z[(size_t)row * 64 + c] * w2[c];
#pragma unroll
    for (int off = 32; off > 0; off >>= 1) v += __shfl_xor(v, off, 64);
    if (c == 0) out[row] = v + b2[0];
}

// ---------------------------------------------------------------------------
extern "C" void kernel_launch(void* const* d_in, const int* in_sizes, int n_in,
                              void* d_out, int out_size, void* d_ws, size_t ws_size,
                              hipStream_t stream) {
    const float* node_feat = (const float*)d_in[0];
    const int*   opcode    = (const int*)d_in[1];
    const int*   ei        = (const int*)d_in[2];
    const float* cf        = (const float*)d_in[3];
    const int*   ncfg      = (const int*)d_in[4];
    const int*   batch     = (const int*)d_in[5];
    const float* emb       = (const float*)d_in[6];
    const float* wl0 = (const float*)d_in[7];
    const float* bl0 = (const float*)d_in[8];
    const float* wr0 = (const float*)d_in[9];
    const float* lw0 = (const float*)d_in[10];
    const float* lb0 = (const float*)d_in[11];
    const float* wl1 = (const float*)d_in[12];
    const float* bl1 = (const float*)d_in[13];
    const float* wr1 = (const float*)d_in[14];
    const float* lw1 = (const float*)d_in[15];
    const float* lb1 = (const float*)d_in[16];
    const float* wl2 = (const float*)d_in[17];
    const float* bl2 = (const float*)d_in[18];
    const float* wr2 = (const float*)d_in[19];
    const float* lw2 = (const float*)d_in[20];
    const float* lb2 = (const float*)d_in[21];
    const float* pw1 = (const float*)d_in[22];
    const float* pb1 = (const float*)d_in[23];
    const float* pw2 = (const float*)d_in[24];
    const float* pb2 = (const float*)d_in[25];

    const int N  = in_sizes[0] / 140;
    const int E  = in_sizes[2] / 2;
    const int B  = in_sizes[4];
    const int BC = in_sizes[3] / 24;
    const int NBUCK = (N + 127) >> 7;

    char* w = (char*)d_ws;
    auto alloc = [&](size_t bytes) {
        void* p = (void*)w;
        w += (bytes + 255) & ~(size_t)255;
        return p;
    };
    int*      bcnt     = (int*)alloc(1024 * 4);
    int*      bo       = (int*)alloc(1025 * 4);
    int*      bfill    = (int*)alloc(1024 * 4);
    uint2*    pairs    = (uint2*)alloc((size_t)2 * E * 8);   // dead after k_bfinal
    int*      rp       = (int*)alloc((size_t)(N + 1) * 4);
    float*    invd     = (float*)alloc((size_t)N * 4);
    int*      csr      = (int*)alloc((size_t)2 * E * 4);
    unsigned* X0       = (unsigned*)alloc((size_t)N * 80 * 4);   // bf16, stride 160
    unsigned* AG0      = (unsigned*)alloc((size_t)N * 80 * 4);
    unsigned* H0       = (unsigned*)alloc((size_t)N * 80 * 4);
    unsigned* T0       = (unsigned*)alloc((size_t)N * 32 * 4);   // bf16, stride 64
    unsigned* T1       = (unsigned*)alloc((size_t)N * 32 * 4);
    unsigned* T2       = (unsigned*)alloc((size_t)N * 32 * 4);
    float*    X3F      = (float*)alloc((size_t)N * 64 * 4);      // final x, f32
    float*    gbuf     = (float*)alloc((size_t)B * 64 * 4);
    float*    zp       = (float*)alloc((size_t)BC * 64 * 4);
    uint4*    Wp0h     = (uint4*)alloc((size_t)10 * 10 * 64 * 16);
    uint4*    Wp0l     = (uint4*)alloc((size_t)4 * 10 * 64 * 16);
    uint4*    Wp1h     = (uint4*)alloc((size_t)4 * 4 * 64 * 16);
    uint4*    Wp1l     = (uint4*)alloc((size_t)4 * 4 * 64 * 16);
    uint4*    Wp2h     = (uint4*)alloc((size_t)4 * 4 * 64 * 16);
    uint4*    Wp2l     = (uint4*)alloc((size_t)4 * 4 * 64 * 16);
    // fp8 x0 copy (N*40 uints = 16MB) aliases pairs (2E*8 = 25.6MB), which is
    // dead once k_bfinal has run (k_concat launches after it).
    unsigned* X08      = (unsigned*)pairs;
    (void)ws_size; (void)n_in; (void)out_size;

    (void)hipMemsetAsync(bcnt, 0, 1024 * 4, stream);
    (void)hipMemsetAsync(gbuf, 0, (size_t)B * 64 * 4, stream);

    // weight pre-pack (tiny)
    k_prep<10, 5, 10, 148><<<(6400 + 255) / 256, 256, 0, stream>>>(wl0, wr0, 148, 148, Wp0h);
    k_prep<10, 5, 4, 64><<<(2560 + 255) / 256, 256, 0, stream>>>(lw0, lw0 + 148 * 64, 148, 148, Wp0l);
    k_prep<4, 2, 4, 64><<<4, 256, 0, stream>>>(wl1, wr1, 64, 64, Wp1h);
    k_prep<4, 2, 4, 64><<<4, 256, 0, stream>>>(lw1, lw1 + 64 * 64, 64, 64, Wp1l);
    k_prep<4, 2, 4, 64><<<4, 256, 0, stream>>>(wl2, wr2, 64, 64, Wp2h);
    k_prep<4, 2, 4, 64><<<4, 256, 0, stream>>>(lw2, lw2 + 64 * 64, 64, 64, Wp2l);

    // bucketed CSR build (before k_concat: X08 aliases pairs)
    const int EB = (E + 4095) / 4096;
    k_bh<<<EB, 256, 0, stream>>>(ei, E, NBUCK, bcnt);
    k_bscan<<<1, 1024, 0, stream>>>(bcnt, NBUCK, bo, bfill);
    k_bscatter<<<EB, 256, 0, stream>>>(ei, E, bfill, pairs);
    k_bfinal<<<NBUCK, 256, 0, stream>>>(pairs, bo, rp, csr, invd, N, NBUCK);

    k_concat<<<(N * 40 + 255) / 256, 256, 0, stream>>>(node_feat, opcode, emb, X0, X08, N);

    const int AGG_GRID  = (N + 3) / 4;
    const int GEMM_GRID = (N + 63) / 64;

    // ---- layer 0 ----
    k_agg160<<<AGG_GRID, 256, 0, stream>>>(X08, rp, csr, invd, AG0, N);
    k_gemm<10, 5, 10, 148, 160, 1, 0, 0><<<GEMM_GRID, 256, 0, stream>>>(
        (const uint4*)AG0, (const uint4*)X0, Wp0h, bl0, H0, N);
    k_gemm<10, 5, 4, 64, 64, 0, 1, 0><<<GEMM_GRID, 256, 0, stream>>>(
        (const uint4*)H0, (const uint4*)X0, Wp0l, lb0, T0, N);

    // ---- layer 1 ----
    k_agg64<<<AGG_GRID, 256, 0, stream>>>(T0, rp, csr, invd, T1, N);
    k_gemm<4, 2, 4, 64, 64, 1, 0, 0><<<GEMM_GRID, 256, 0, stream>>>(
        (const uint4*)T1, (const uint4*)T0, Wp1h, bl1, T2, N);
    k_gemm<4, 2, 4, 64, 64, 0, 1, 0><<<GEMM_GRID, 256, 0, stream>>>(
        (const uint4*)T2, (const uint4*)T0, Wp1l, lb1, T1, N);

    // ---- layer 2 ----
    k_agg64<<<AGG_GRID, 256, 0, stream>>>(T1, rp, csr, invd, T0, N);
    k_gemm<4, 2, 4, 64, 64, 1, 0, 0><<<GEMM_GRID, 256, 0, stream>>>(
        (const uint4*)T0, (const uint4*)T1, Wp2h, bl2, T2, N);
    k_gemm<4, 2, 4, 64, 64, 0, 1, 1><<<GEMM_GRID, 256, 0, stream>>>(
        (const uint4*)T2, (const uint4*)T1, Wp2l, lb2, X3F, N);

    // pool + post MLP
    k_pool<<<(N + 255) / 256, 256, 0, stream>>>(X3F, batch, gbuf, N);
    k_post1<<<(BC * 64 + 255) / 256, 256, 0, stream>>>(gbuf, cf, ncfg, pw1, pb1, zp, BC, B);
    k_post2<<<(BC + 3) / 4, 256, 0, stream>>>(zp, pw2, pb2, (float*)d_out, BC);
}

// Round 8
// 531.265 us; speedup vs baseline: 3.2613x; 1.0271x over previous
//
#include <hip/hip_runtime.h>
#include <cstdint>
#include <cstddef>

// ---------------------------------------------------------------------------
// LateJoinSAGE round 8: round 7 + fp8 gather for the 64-dim aggregations too.
// x1/x2 get fp8 copies (k_cvt8, 6.4MB each, LLC-resident); k_agg64_8 gathers
// one 64B cache line per neighbor row (4 neighbors per full-wave load).
// ---------------------------------------------------------------------------

#define LRELU(v) ((v) > 0.f ? (v) : 0.01f * (v))

typedef __attribute__((ext_vector_type(8))) short bf16x8;
typedef __attribute__((ext_vector_type(4))) float f32x4;
typedef float floatx2 __attribute__((ext_vector_type(2)));

union U4B8 {
    uint4 u;
    bf16x8 b;
};

__device__ inline unsigned bf16_rn(float x) {
    unsigned u = __float_as_uint(x);
    return (u + 0x7fffu + ((u >> 16) & 1u)) >> 16;
}
__device__ inline unsigned pack2(float lo, float hi) {
    return bf16_rn(lo) | (bf16_rn(hi) << 16);
}
__device__ inline float2 up2(unsigned v) {
    return make_float2(__uint_as_float(v << 16), __uint_as_float(v & 0xffff0000u));
}

// ---------------- fp8 e4m3 helpers ----------------
__device__ inline float e4m3_to_f32(unsigned b) {
    float v = __uint_as_float((b & 0x7fu) << 20) * 0x1p120f;
    return __uint_as_float(__float_as_uint(v) | ((b & 0x80u) << 24));
}

template <bool HI>
__device__ inline floatx2 fp8x2_dec(unsigned v) {
#if __has_builtin(__builtin_amdgcn_cvt_pk_f32_fp8)
    return __builtin_amdgcn_cvt_pk_f32_fp8((int)v, HI);
#else
    unsigned w = HI ? (v >> 16) : v;
    floatx2 r;
    r.x = e4m3_to_f32(w & 0xffu);
    r.y = e4m3_to_f32((w >> 8) & 0xffu);
    return r;
#endif
}

__device__ inline unsigned char f32_to_e4m3_sw(float f) {
    unsigned u = __float_as_uint(f);
    unsigned s = (u >> 24) & 0x80u;
    float a = fabsf(f);
    if (a > 448.f) a = 448.f;
    unsigned b = __float_as_uint(a);
    int exp = (int)(b >> 23) - 127;
    unsigned r;
    if (exp < -9) {
        r = 0;
    } else if (exp >= -6) {
        unsigned m = b & 0x7fffffu;
        unsigned keep = m >> 20;
        unsigned rb = (m >> 19) & 1u;
        unsigned sticky = (m & 0x7ffffu) ? 1u : 0u;
        unsigned inc = rb & (sticky | (keep & 1u));
        unsigned em = (((unsigned)(exp + 7)) << 3) | keep;
        em += inc;
        if (em > 0x7eu) em = 0x7eu;
        r = em;
    } else {
        float t = a * 512.f;
        int q = (int)(t + 0.5f);
        r = (q > 7) ? 0x08u : (unsigned)q;
    }
    return (unsigned char)(r | s);
}

__device__ inline unsigned fp8x4_enc(float f0, float f1, float f2, float f3) {
#if __has_builtin(__builtin_amdgcn_cvt_pk_fp8_f32)
    int pk = __builtin_amdgcn_cvt_pk_fp8_f32(f0, f1, 0, false);
    pk = __builtin_amdgcn_cvt_pk_fp8_f32(f2, f3, pk, true);
    return (unsigned)pk;
#else
    return (unsigned)f32_to_e4m3_sw(f0) | ((unsigned)f32_to_e4m3_sw(f1) << 8) |
           ((unsigned)f32_to_e4m3_sw(f2) << 16) | ((unsigned)f32_to_e4m3_sw(f3) << 24);
#endif
}

// ---------------- x0 concat -> bf16 (stride 160) + fp8 (stride 160B) -------
__global__ void k_concat(const float* __restrict__ nf, const int* __restrict__ opc,
                         const float* __restrict__ emb, unsigned* __restrict__ x0,
                         unsigned* __restrict__ x8, int n) {
    int idx = blockIdx.x * 256 + threadIdx.x;
    if (idx >= n * 40) return;
    int node = idx / 40;
    int u = idx - node * 40;
    float f[4];
#pragma unroll
    for (int j = 0; j < 4; j++) {
        int ft = 4 * u + j;
        float v = 0.f;
        if (ft < 140) v = nf[(size_t)node * 140 + ft];
        else if (ft < 148) v = emb[opc[node] * 8 + (ft - 140)];
        f[j] = v;
    }
    ((uint2*)x0)[idx] = make_uint2(pack2(f[0], f[1]), pack2(f[2], f[3]));
    x8[idx] = fp8x4_enc(f[0], f[1], f[2], f[3]);
}

// ---------------- bf16 (stride 32 uints) -> fp8 (16 uints) ----------------
__global__ void k_cvt8(const unsigned* __restrict__ xb, unsigned* __restrict__ x8,
                       int n) {
    int idx = blockIdx.x * 256 + threadIdx.x;
    if (idx >= n * 16) return;
    uint2 v = ((const uint2*)xb)[idx];
    float2 ab = up2(v.x);
    float2 cd = up2(v.y);
    x8[idx] = fp8x4_enc(ab.x, ab.y, cd.x, cd.y);
}

// ---------------- bucketed CSR build ----------------
__global__ __launch_bounds__(256) void k_bh(const int* __restrict__ ei, int E,
                                            int NBUCK, int* __restrict__ bcnt) {
    __shared__ int h[1024];
    int t = threadIdx.x;
    for (int i = t; i < 1024; i += 256) h[i] = 0;
    __syncthreads();
    int e0 = blockIdx.x * 4096, e1 = min(E, e0 + 4096);
    for (int e = e0 + t; e < e1; e += 256) {
        int a = ei[2 * e], b = ei[2 * e + 1];
        atomicAdd(&h[b >> 7], 1);
        atomicAdd(&h[a >> 7], 1);
    }
    __syncthreads();
    for (int i = t; i < NBUCK; i += 256)
        if (h[i]) atomicAdd(&bcnt[i], h[i]);
}

__global__ void k_bscan(const int* __restrict__ bcnt, int NBUCK,
                        int* __restrict__ bo, int* __restrict__ bfill) {
    __shared__ int sm[1024];
    int t = threadIdx.x;
    int v = (t < NBUCK) ? bcnt[t] : 0;
    sm[t] = v;
    __syncthreads();
    for (int off = 1; off < 1024; off <<= 1) {
        int u = 0;
        if (t >= off) u = sm[t - off];
        __syncthreads();
        sm[t] += u;
        __syncthreads();
    }
    if (t < NBUCK) {
        int ex = sm[t] - v;
        bo[t] = ex;
        bfill[t] = ex;
    }
    if (t == NBUCK - 1) bo[NBUCK] = sm[t];
}

__global__ __launch_bounds__(256) void k_bscatter(const int* __restrict__ ei, int E,
                                                  int* __restrict__ bfill,
                                                  uint2* __restrict__ pairs) {
    __shared__ int hist[1024], lbo[1024], gb[1024], cur[1024];
    __shared__ int wsum[4];
    __shared__ int stageD[8192];
    __shared__ int stageS[8192];
    int t = threadIdx.x;
    for (int i = t; i < 1024; i += 256) hist[i] = 0;
    __syncthreads();
    int e0 = blockIdx.x * 4096, e1 = min(E, e0 + 4096);
    for (int e = e0 + t; e < e1; e += 256) {
        int a = ei[2 * e], b = ei[2 * e + 1];
        atomicAdd(&hist[b >> 7], 1);
        atomicAdd(&hist[a >> 7], 1);
    }
    __syncthreads();
    int b4 = t * 4;
    int c0 = hist[b4], c1 = hist[b4 + 1], c2 = hist[b4 + 2], c3 = hist[b4 + 3];
    int ms = c0 + c1 + c2 + c3;
    int lane = t & 63, wv = t >> 6;
    int v = ms;
#pragma unroll
    for (int off = 1; off < 64; off <<= 1) {
        int u = __shfl_up(v, off, 64);
        if (lane >= off) v += u;
    }
    if (lane == 63) wsum[wv] = v;
    __syncthreads();
    int wb = 0;
    for (int i = 0; i < wv; i++) wb += wsum[i];
    int ex = wb + v - ms;
    lbo[b4] = ex;
    lbo[b4 + 1] = ex + c0;
    lbo[b4 + 2] = ex + c0 + c1;
    lbo[b4 + 3] = ex + c0 + c1 + c2;
    if (c0) gb[b4 + 0] = atomicAdd(&bfill[b4 + 0], c0);
    if (c1) gb[b4 + 1] = atomicAdd(&bfill[b4 + 1], c1);
    if (c2) gb[b4 + 2] = atomicAdd(&bfill[b4 + 2], c2);
    if (c3) gb[b4 + 3] = atomicAdd(&bfill[b4 + 3], c3);
    cur[b4] = 0;
    cur[b4 + 1] = 0;
    cur[b4 + 2] = 0;
    cur[b4 + 3] = 0;
    __syncthreads();
    for (int e = e0 + t; e < e1; e += 256) {
        int a = ei[2 * e], b = ei[2 * e + 1];
        int bk = b >> 7;
        int r = atomicAdd(&cur[bk], 1);
        int p = lbo[bk] + r;
        stageD[p] = b;
        stageS[p] = a;
        bk = a >> 7;
        r = atomicAdd(&cur[bk], 1);
        p = lbo[bk] + r;
        stageD[p] = a;
        stageS[p] = b;
    }
    __syncthreads();
    int tot = 2 * (e1 - e0);
    for (int i = t; i < tot; i += 256) {
        int d = stageD[i];
        int bk = d >> 7;
        pairs[gb[bk] + (i - lbo[bk])] = make_uint2((unsigned)d, (unsigned)stageS[i]);
    }
}

__global__ __launch_bounds__(256) void k_bfinal(const uint2* __restrict__ pairs,
                                                const int* __restrict__ bo,
                                                int* __restrict__ rp,
                                                int* __restrict__ csr,
                                                float* __restrict__ invd,
                                                int N, int NBUCK) {
    __shared__ int hist[128], ls[128], cur[128];
    __shared__ unsigned outS[6144];
    int t = threadIdx.x;
    int bk = blockIdx.x;
    int n0 = bk << 7;
    int nn = min(128, N - n0);
    int base = bo[bk], cnt = bo[bk + 1] - base;
    if (t < 128) {
        hist[t] = 0;
        cur[t] = 0;
    }
    __syncthreads();
    for (int i = t; i < cnt; i += 256) atomicAdd(&hist[(int)pairs[base + i].x - n0], 1);
    __syncthreads();
    if (t == 0) {
        int run = 0;
        for (int i = 0; i < 128; i++) {
            ls[i] = run;
            run += hist[i];
        }
    }
    __syncthreads();
    if (t < nn) {
        int node = n0 + t;
        rp[node] = base + ls[t];
        invd[node] = 1.0f / fmaxf((float)hist[t], 1.0f);
    }
    if (bk == NBUCK - 1 && t == 0) rp[N] = base + cnt;
    bool inl = (cnt <= 6144);
    for (int i = t; i < cnt; i += 256) {
        uint2 pr = pairs[base + i];
        int loc = (int)pr.x - n0;
        int r = atomicAdd(&cur[loc], 1);
        int pos = ls[loc] + r;
        if (inl) outS[pos] = pr.y;
        else csr[base + pos] = (int)pr.y;
    }
    __syncthreads();
    if (inl)
        for (int i = t; i < cnt; i += 256) csr[base + i] = (int)outS[i];
}

// ---------------- layer-0 aggregation from fp8 rows (40 uints/row) ---------
__global__ __launch_bounds__(256) void k_agg160(
    const unsigned* __restrict__ x8, const int* __restrict__ rp,
    const int* __restrict__ csr, const float* __restrict__ invd,
    unsigned* __restrict__ agg, int n) {
    int wave = threadIdx.x >> 6;
    int l = threadIdx.x & 63;
    int node = blockIdx.x * 4 + wave;
    if (node >= n) return;
    int p = l & 31;
    int h = l >> 5;
    int eg = l >> 3;
    int eq = l & 7;
    float am[4] = {0.f, 0.f, 0.f, 0.f};
    float ae[4] = {0.f, 0.f, 0.f, 0.f};
    int s = rp[node], e2 = rp[node + 1];
    int j = s;
    for (; j + 8 <= e2; j += 8) {
#pragma unroll
        for (int i = 0; i < 4; i++) {
            int u = csr[j + 2 * i + h];
            unsigned v = x8[(size_t)u * 40 + p];
            floatx2 lo = fp8x2_dec<false>(v);
            floatx2 hi = fp8x2_dec<true>(v);
            am[0] += lo.x;
            am[1] += lo.y;
            am[2] += hi.x;
            am[3] += hi.y;
        }
        int ue = csr[j + eg];
        unsigned v = x8[(size_t)ue * 40 + 32 + eq];
        floatx2 lo = fp8x2_dec<false>(v);
        floatx2 hi = fp8x2_dec<true>(v);
        ae[0] += lo.x;
        ae[1] += lo.y;
        ae[2] += hi.x;
        ae[3] += hi.y;
    }
    for (; j < e2; j++) {
        int u = csr[j];
        if (l < 32) {
            unsigned v = x8[(size_t)u * 40 + p];
            floatx2 lo = fp8x2_dec<false>(v);
            floatx2 hi = fp8x2_dec<true>(v);
            am[0] += lo.x;
            am[1] += lo.y;
            am[2] += hi.x;
            am[3] += hi.y;
        } else if (l < 40) {
            unsigned v = x8[(size_t)u * 40 + 32 + eq];
            floatx2 lo = fp8x2_dec<false>(v);
            floatx2 hi = fp8x2_dec<true>(v);
            ae[0] += lo.x;
            ae[1] += lo.y;
            ae[2] += hi.x;
            ae[3] += hi.y;
        }
    }
#pragma unroll
    for (int r = 0; r < 4; r++) am[r] += __shfl_xor(am[r], 32, 64);
#pragma unroll
    for (int r = 0; r < 4; r++) {
        ae[r] += __shfl_xor(ae[r], 8, 64);
        ae[r] += __shfl_xor(ae[r], 16, 64);
        ae[r] += __shfl_xor(ae[r], 32, 64);
    }
    float iv = invd[node];
    unsigned* row = agg + (size_t)node * 80;
    if (l < 32)
        ((uint2*)row)[p] = make_uint2(pack2(am[0] * iv, am[1] * iv),
                                      pack2(am[2] * iv, am[3] * iv));
    if (l < 8)
        ((uint2*)(row + 64))[eq] = make_uint2(pack2(ae[0] * iv, ae[1] * iv),
                                              pack2(ae[2] * iv, ae[3] * iv));
}

// ---------------- 64-dim aggregation from fp8 rows (16 uints = 1 line) -----
// 4 neighbors per full-wave load: 16 lanes per row, 4 features per lane.
__global__ __launch_bounds__(256) void k_agg64_8(
    const unsigned* __restrict__ x8, const int* __restrict__ rp,
    const int* __restrict__ csr, const float* __restrict__ invd,
    unsigned* __restrict__ agg, int n) {
    int wave = threadIdx.x >> 6;
    int l = threadIdx.x & 63;
    int node = blockIdx.x * 4 + wave;
    if (node >= n) return;
    int p = l & 15;        // uint within row (features 4p..4p+3)
    int g = l >> 4;        // neighbor slot 0..3
    float a[4] = {0.f, 0.f, 0.f, 0.f};
    int s = rp[node], e2 = rp[node + 1];
    int j = s;
    for (; j + 8 <= e2; j += 8) {
        int u0 = csr[j + g];
        int u1 = csr[j + 4 + g];
        unsigned v0 = x8[(size_t)u0 * 16 + p];
        unsigned v1 = x8[(size_t)u1 * 16 + p];
        floatx2 lo0 = fp8x2_dec<false>(v0);
        floatx2 hi0 = fp8x2_dec<true>(v0);
        floatx2 lo1 = fp8x2_dec<false>(v1);
        floatx2 hi1 = fp8x2_dec<true>(v1);
        a[0] += lo0.x + lo1.x;
        a[1] += lo0.y + lo1.y;
        a[2] += hi0.x + hi1.x;
        a[3] += hi0.y + hi1.y;
    }
    for (; j < e2; j += 4) {
        if (j + g < e2) {
            int u = csr[j + g];
            unsigned v = x8[(size_t)u * 16 + p];
            floatx2 lo = fp8x2_dec<false>(v);
            floatx2 hi = fp8x2_dec<true>(v);
            a[0] += lo.x;
            a[1] += lo.y;
            a[2] += hi.x;
            a[3] += hi.y;
        }
    }
#pragma unroll
    for (int r = 0; r < 4; r++) {
        a[r] += __shfl_xor(a[r], 16, 64);
        a[r] += __shfl_xor(a[r], 32, 64);
    }
    if (l < 16) {
        float iv = invd[node];
        ((uint2*)(agg + (size_t)node * 32))[p] =
            make_uint2(pack2(a[0] * iv, a[1] * iv), pack2(a[2] * iv, a[3] * iv));
    }
}

// ---------------- weight pre-pack into B-fragment order --------------------
template <int KS, int KSH, int CT, int C>
__global__ void k_prep(const float* __restrict__ W1, const float* __restrict__ W2,
                       int K1, int K2, uint4* __restrict__ Wp) {
    int idx = blockIdx.x * 256 + threadIdx.x;
    if (idx >= CT * KS * 64) return;
    int l = idx & 63;
    int ks = (idx >> 6) % KS;
    int ct = idx / (KS * 64);
    int col = ct * 16 + (l & 15);
    int kbase = ks * 32 + (l >> 4) * 8;
    unsigned short v[8];
#pragma unroll
    for (int j = 0; j < 8; j++) {
        int k = kbase + j;
        float f = 0.f;
        if (col < C) {
            if (k < KSH * 32) {
                if (k < K1) f = W1[(size_t)k * C + col];
            } else {
                int k2 = k - KSH * 32;
                if (k2 < K2) f = W2[(size_t)k2 * C + col];
            }
        }
        v[j] = (unsigned short)bf16_rn(f);
    }
    uint4 o;
    o.x = v[0] | ((unsigned)v[1] << 16);
    o.y = v[2] | ((unsigned)v[3] << 16);
    o.z = v[4] | ((unsigned)v[5] << 16);
    o.w = v[6] | ((unsigned)v[7] << 16);
    Wp[idx] = o;
}

// ---------------- MFMA GEMM: out = post([A|B] @ Wp + bias) -----------------
template <int KS, int KSH, int CT, int C, int OST, int NORM, int ACT, int OUTF>
__global__ __launch_bounds__(256) void k_gemm(
    const uint4* __restrict__ A, const uint4* __restrict__ Bb,
    const uint4* __restrict__ Wp, const float* __restrict__ bias,
    void* __restrict__ outv, int n) {
    int l = threadIdx.x & 63;
    int wv = threadIdx.x >> 6;
    int rb = blockIdx.x * 64 + wv * 16;
    int rowA = rb + (l & 15);
    if (rowA >= n) rowA = n - 1;           // clamp; stores are guarded
    int koct = l >> 4;
    const int strideU = KSH * 4;           // uint4 per row
    size_t baseA = (size_t)rowA * strideU + koct;

    f32x4 acc[CT];
#pragma unroll
    for (int ct = 0; ct < CT; ct++) acc[ct] = (f32x4){0.f, 0.f, 0.f, 0.f};

#pragma unroll
    for (int ks = 0; ks < KS; ks++) {
        U4B8 a;
        a.u = (ks < KSH) ? A[baseA + ks * 4] : Bb[baseA + (ks - KSH) * 4];
#pragma unroll
        for (int ct = 0; ct < CT; ct++) {
            U4B8 b;
            b.u = Wp[(ct * KS + ks) * 64 + l];
            acc[ct] = __builtin_amdgcn_mfma_f32_16x16x32_bf16(a.b, b.b, acc[ct], 0, 0, 0);
        }
    }

    int cid = l & 15;
    int grp = l >> 4;
#pragma unroll
    for (int ct = 0; ct < CT; ct++) {
        int col = ct * 16 + cid;
        float bv = (col < C) ? bias[col] : 0.f;
#pragma unroll
        for (int r = 0; r < 4; r++) acc[ct][r] += bv;
    }

    if (NORM) {
        float ss[4];
#pragma unroll
        for (int r = 0; r < 4; r++) {
            ss[r] = 0.f;
#pragma unroll
            for (int ct = 0; ct < CT; ct++) ss[r] += acc[ct][r] * acc[ct][r];
        }
#pragma unroll
        for (int off = 1; off < 16; off <<= 1) {
#pragma unroll
            for (int r = 0; r < 4; r++) ss[r] += __shfl_xor(ss[r], off, 64);
        }
#pragma unroll
        for (int r = 0; r < 4; r++) {
            float sc = 1.0f / fmaxf(sqrtf(ss[r]), 1e-12f);
#pragma unroll
            for (int ct = 0; ct < CT; ct++) acc[ct][r] *= sc;
        }
    }

    if (ACT) {
#pragma unroll
        for (int ct = 0; ct < CT; ct++)
#pragma unroll
            for (int r = 0; r < 4; r++) acc[ct][r] = LRELU(acc[ct][r]);
    }

#pragma unroll
    for (int r = 0; r < 4; r++) {
        int row = rb + grp * 4 + r;
        if (row >= n) continue;
        if (OUTF) {
            float* o = (float*)outv;
#pragma unroll
            for (int ct = 0; ct < CT; ct++) {
                int col = ct * 16 + cid;
                if (col < OST) o[(size_t)row * OST + col] = acc[ct][r];
            }
        } else {
            unsigned short* o = (unsigned short*)outv;
#pragma unroll
            for (int ct = 0; ct < CT; ct++) {
                int col = ct * 16 + cid;
                if (col < OST) o[(size_t)row * OST + col] = (unsigned short)bf16_rn(acc[ct][r]);
            }
        }
    }
}

// ---------------- global add-pool: wave per 64 rows, coalesced -------------
__global__ __launch_bounds__(256) void k_pool(const float* __restrict__ x,
                                              const int* __restrict__ batch,
                                              float* __restrict__ g, int n) {
    __shared__ float sm[8][64];
    __shared__ int sb[8];
    int lane = threadIdx.x & 63;
    int wv = threadIdx.x >> 6;
    int base = blockIdx.x * 256 + wv * 64;
    float a0 = 0.f, a1 = 0.f;
    int b0 = -1, b1 = -1;
    int end = (base + 64 < n) ? base + 64 : n;
    for (int row = base; row < end; row++) {
        int bg = batch[row];
        float v = x[(size_t)row * 64 + lane];
        if (b0 < 0) b0 = bg;
        if (bg == b0) a0 += v;
        else { if (b1 < 0) b1 = bg; a1 += v; }
    }
    sm[wv * 2 + 0][lane] = a0;
    sm[wv * 2 + 1][lane] = a1;
    if (lane == 0) {
        sb[wv * 2 + 0] = b0;
        sb[wv * 2 + 1] = b1;
    }
    __syncthreads();
    if (wv == 0) {
        float c0 = 0.f, c1 = 0.f;
        int d0 = -1, d1 = -1;
#pragma unroll
        for (int s = 0; s < 8; s++) {
            int bg = sb[s];
            if (bg < 0) continue;
            float v = sm[s][lane];
            if (d0 < 0) d0 = bg;
            if (bg == d0) c0 += v;
            else { if (d1 < 0) d1 = bg; c1 += v; }
        }
        if (d0 >= 0) atomicAdd(&g[d0 * 64 + lane], c0);
        if (d1 >= 0) atomicAdd(&g[d1 * 64 + lane], c1);
    }
}

// ---------------- post MLP ----------------
__global__ void k_post1(const float* __restrict__ g, const float* __restrict__ cf,
                        const int* __restrict__ ncfg, const float* __restrict__ w1,
                        const float* __restrict__ b1, float* __restrict__ z,
                        int BC, int B) {
    int idx = blockIdx.x * 256 + threadIdx.x;
    if (idx >= BC * 64) return;
    int row = idx >> 6, c = idx & 63;
    int gsum = 0, gid = B - 1;
    for (int b2 = 0; b2 < B; b2++) {
        int ns = ncfg[b2];
        if (row < gsum + ns) { gid = b2; break; }
        gsum += ns;
    }
    float acc = b1[c];
#pragma unroll 4
    for (int k = 0; k < 64; k++) acc += g[gid * 64 + k] * w1[k * 64 + c];
#pragma unroll 4
    for (int k = 0; k < 24; k++) acc += cf[(size_t)row * 24 + k] * w1[(64 + k) * 64 + c];
    z[idx] = LRELU(acc);
}

__global__ void k_post2(const float* __restrict__ z, const float* __restrict__ w2,
                        const float* __restrict__ b2, float* __restrict__ out, int BC) {
    int row = blockIdx.x * 4 + (threadIdx.x >> 6);
    if (row >= BC) return;
    int c = threadIdx.x & 63;
    float v = z[(size_t)row * 64 + c] * w2[c];
#pragma unroll
    for (int off = 32; off > 0; off >>= 1) v += __shfl_xor(v, off, 64);
    if (c == 0) out[row] = v + b2[0];
}

// ---------------------------------------------------------------------------
extern "C" void kernel_launch(void* const* d_in, const int* in_sizes, int n_in,
                              void* d_out, int out_size, void* d_ws, size_t ws_size,
                              hipStream_t stream) {
    const float* node_feat = (const float*)d_in[0];
    const int*   opcode    = (const int*)d_in[1];
    const int*   ei        = (const int*)d_in[2];
    const float* cf        = (const float*)d_in[3];
    const int*   ncfg      = (const int*)d_in[4];
    const int*   batch     = (const int*)d_in[5];
    const float* emb       = (const float*)d_in[6];
    const float* wl0 = (const float*)d_in[7];
    const float* bl0 = (const float*)d_in[8];
    const float* wr0 = (const float*)d_in[9];
    const float* lw0 = (const float*)d_in[10];
    const float* lb0 = (const float*)d_in[11];
    const float* wl1 = (const float*)d_in[12];
    const float* bl1 = (const float*)d_in[13];
    const float* wr1 = (const float*)d_in[14];
    const float* lw1 = (const float*)d_in[15];
    const float* lb1 = (const float*)d_in[16];
    const float* wl2 = (const float*)d_in[17];
    const float* bl2 = (const float*)d_in[18];
    const float* wr2 = (const float*)d_in[19];
    const float* lw2 = (const float*)d_in[20];
    const float* lb2 = (const float*)d_in[21];
    const float* pw1 = (const float*)d_in[22];
    const float* pb1 = (const float*)d_in[23];
    const float* pw2 = (const float*)d_in[24];
    const float* pb2 = (const float*)d_in[25];

    const int N  = in_sizes[0] / 140;
    const int E  = in_sizes[2] / 2;
    const int B  = in_sizes[4];
    const int BC = in_sizes[3] / 24;
    const int NBUCK = (N + 127) >> 7;

    char* w = (char*)d_ws;
    auto alloc = [&](size_t bytes) {
        void* p = (void*)w;
        w += (bytes + 255) & ~(size_t)255;
        return p;
    };
    int*      bcnt     = (int*)alloc(1024 * 4);
    int*      bo       = (int*)alloc(1025 * 4);
    int*      bfill    = (int*)alloc(1024 * 4);
    uint2*    pairs    = (uint2*)alloc((size_t)2 * E * 8);   // dead after k_bfinal
    int*      rp       = (int*)alloc((size_t)(N + 1) * 4);
    float*    invd     = (float*)alloc((size_t)N * 4);
    int*      csr      = (int*)alloc((size_t)2 * E * 4);
    unsigned* X0       = (unsigned*)alloc((size_t)N * 80 * 4);   // bf16, stride 160
    unsigned* AG0      = (unsigned*)alloc((size_t)N * 80 * 4);
    unsigned* H0       = (unsigned*)alloc((size_t)N * 80 * 4);
    unsigned* T0       = (unsigned*)alloc((size_t)N * 32 * 4);   // bf16, stride 64
    unsigned* T1       = (unsigned*)alloc((size_t)N * 32 * 4);
    unsigned* T2       = (unsigned*)alloc((size_t)N * 32 * 4);
    unsigned* G8       = (unsigned*)alloc((size_t)N * 16 * 4);   // fp8 64-dim gather buf
    float*    X3F      = (float*)alloc((size_t)N * 64 * 4);      // final x, f32
    float*    gbuf     = (float*)alloc((size_t)B * 64 * 4);
    float*    zp       = (float*)alloc((size_t)BC * 64 * 4);
    uint4*    Wp0h     = (uint4*)alloc((size_t)10 * 10 * 64 * 16);
    uint4*    Wp0l     = (uint4*)alloc((size_t)4 * 10 * 64 * 16);
    uint4*    Wp1h     = (uint4*)alloc((size_t)4 * 4 * 64 * 16);
    uint4*    Wp1l     = (uint4*)alloc((size_t)4 * 4 * 64 * 16);
    uint4*    Wp2h     = (uint4*)alloc((size_t)4 * 4 * 64 * 16);
    uint4*    Wp2l     = (uint4*)alloc((size_t)4 * 4 * 64 * 16);
    // fp8 x0 copy (N*40 uints = 16MB) aliases pairs (2E*8 = 25.6MB), dead
    // once k_bfinal has run (k_concat launches after it).
    unsigned* X08      = (unsigned*)pairs;
    (void)ws_size; (void)n_in; (void)out_size;

    (void)hipMemsetAsync(bcnt, 0, 1024 * 4, stream);
    (void)hipMemsetAsync(gbuf, 0, (size_t)B * 64 * 4, stream);

    // weight pre-pack (tiny)
    k_prep<10, 5, 10, 148><<<(6400 + 255) / 256, 256, 0, stream>>>(wl0, wr0, 148, 148, Wp0h);
    k_prep<10, 5, 4, 64><<<(2560 + 255) / 256, 256, 0, stream>>>(lw0, lw0 + 148 * 64, 148, 148, Wp0l);
    k_prep<4, 2, 4, 64><<<4, 256, 0, stream>>>(wl1, wr1, 64, 64, Wp1h);
    k_prep<4, 2, 4, 64><<<4, 256, 0, stream>>>(lw1, lw1 + 64 * 64, 64, 64, Wp1l);
    k_prep<4, 2, 4, 64><<<4, 256, 0, stream>>>(wl2, wr2, 64, 64, Wp2h);
    k_prep<4, 2, 4, 64><<<4, 256, 0, stream>>>(lw2, lw2 + 64 * 64, 64, 64, Wp2l);

    // bucketed CSR build (before k_concat: X08 aliases pairs)
    const int EB = (E + 4095) / 4096;
    k_bh<<<EB, 256, 0, stream>>>(ei, E, NBUCK, bcnt);
    k_bscan<<<1, 1024, 0, stream>>>(bcnt, NBUCK, bo, bfill);
    k_bscatter<<<EB, 256, 0, stream>>>(ei, E, bfill, pairs);
    k_bfinal<<<NBUCK, 256, 0, stream>>>(pairs, bo, rp, csr, invd, N, NBUCK);

    k_concat<<<(N * 40 + 255) / 256, 256, 0, stream>>>(node_feat, opcode, emb, X0, X08, N);

    const int AGG_GRID  = (N + 3) / 4;
    const int GEMM_GRID = (N + 63) / 64;
    const int CVT_GRID  = (N * 16 + 255) / 256;

    // ---- layer 0 ----
    k_agg160<<<AGG_GRID, 256, 0, stream>>>(X08, rp, csr, invd, AG0, N);
    k_gemm<10, 5, 10, 148, 160, 1, 0, 0><<<GEMM_GRID, 256, 0, stream>>>(
        (const uint4*)AG0, (const uint4*)X0, Wp0h, bl0, H0, N);
    k_gemm<10, 5, 4, 64, 64, 0, 1, 0><<<GEMM_GRID, 256, 0, stream>>>(
        (const uint4*)H0, (const uint4*)X0, Wp0l, lb0, T0, N);

    // ---- layer 1 ----
    k_cvt8<<<CVT_GRID, 256, 0, stream>>>(T0, G8, N);
    k_agg64_8<<<AGG_GRID, 256, 0, stream>>>(G8, rp, csr, invd, T1, N);
    k_gemm<4, 2, 4, 64, 64, 1, 0, 0><<<GEMM_GRID, 256, 0, stream>>>(
        (const uint4*)T1, (const uint4*)T0, Wp1h, bl1, T2, N);
    k_gemm<4, 2, 4, 64, 64, 0, 1, 0><<<GEMM_GRID, 256, 0, stream>>>(
        (const uint4*)T2, (const uint4*)T0, Wp1l, lb1, T1, N);

    // ---- layer 2 ----
    k_cvt8<<<CVT_GRID, 256, 0, stream>>>(T1, G8, N);
    k_agg64_8<<<AGG_GRID, 256, 0, stream>>>(G8, rp, csr, invd, T0, N);
    k_gemm<4, 2, 4, 64, 64, 1, 0, 0><<<GEMM_GRID, 256, 0, stream>>>(
        (const uint4*)T0, (const uint4*)T1, Wp2h, bl2, T2, N);
    k_gemm<4, 2, 4, 64, 64, 0, 1, 1><<<GEMM_GRID, 256, 0, stream>>>(
        (const uint4*)T2, (const uint4*)T1, Wp2l, lb2, X3F, N);

    // pool + post MLP
    k_pool<<<(N + 255) / 256, 256, 0, stream>>>(X3F, batch, gbuf, N);
    k_post1<<<(BC * 64 + 255) / 256, 256, 0, stream>>>(gbuf, cf, ncfg, pw1, pb1, zp, BC, B);
    k_post2<<<(BC + 3) / 4, 256, 0, stream>>>(zp, pw2, pb2, (float*)d_out, BC);
}